// Round 14
// baseline (159.258 us; speedup 1.0000x reference)
//
#include <hip/hip_runtime.h>
#include <stdint.h>

#define NT 4096      // B*S rows of activations
#define SQ 2048      // sequence length (queries; SE is also 2048)
#define DM 512       // model dim

typedef __attribute__((ext_vector_type(4))) float          f32x4_t;
typedef __attribute__((ext_vector_type(8))) short          bf16x8_t;
typedef __attribute__((ext_vector_type(8))) unsigned short u16x8_t;
typedef __attribute__((ext_vector_type(4))) unsigned int   u32x4_t;

#define QSCALE 0.18033688011112042f   // 0.125 * log2(e): softmax via 2^x

__device__ __forceinline__ unsigned short f2bf(float f) {
  unsigned int u = __float_as_uint(f);
  u = u + 0x7FFFu + ((u >> 16) & 1u);   // round-to-nearest-even
  return (unsigned short)(u >> 16);
}
__device__ __forceinline__ float bf2f(unsigned short u) {
  return __uint_as_float((unsigned int)u << 16);
}
__device__ __forceinline__ unsigned int cvtpk(float lo, float hi) {
  unsigned int r;
  asm("v_cvt_pk_bf16_f32 %0, %1, %2" : "=v"(r) : "v"(lo), "v"(hi));
  return r;
}
__device__ __forceinline__ float exp2fast(float x) {
  float r;
  asm("v_exp_f32 %0, %1" : "=v"(r) : "v"(x));   // 2^x
  return r;
}

__device__ __forceinline__ void gload16(const void* g, void* l) {
  __builtin_amdgcn_global_load_lds(
      (__attribute__((address_space(1))) void*)(g),
      (__attribute__((address_space(3))) void*)(l), 16, 0, 0);
}

#define MFMA16(A, B, C) __builtin_amdgcn_mfma_f32_16x16x32_bf16((A), (B), (C), 0, 0, 0)

// ---------------- fused preprocessing: cvt x/enc + 10 weight transposes + bias pack ----------------
__global__ void __launch_bounds__(256) prep_all(
    const float* xs, unsigned short* xd, const float* es, unsigned short* ed,
    const float* s0, const float* s1, const float* s2, const float* s3,
    const float* s4, const float* s5, const float* s6, const float* s7,
    unsigned short* d0, unsigned short* d1, unsigned short* d2, unsigned short* d3,
    unsigned short* d4, unsigned short* d5, unsigned short* d6, unsigned short* d7,
    const float* fw1, unsigned short* w1t, const float* fw2, unsigned short* w2t,
    const float* q1, const float* k1, const float* v1,
    const float* q2, const float* k2, const float* v2,
    float* bqkv1, float* bq2, float* bkv2) {
  __shared__ float t[32][33];
  const int bid = blockIdx.x, tid = threadIdx.x;
  if (bid < 2048) {                       // fp32 -> bf16 conversions
    const float* src = bid < 1024 ? xs : es;
    unsigned short* dst = bid < 1024 ? xd : ed;
    int i = ((bid & 1023) * 256 + tid) * 8;
    f32x4_t a = *(const f32x4_t*)(src + i);
    f32x4_t b = *(const f32x4_t*)(src + i + 4);
    u16x8_t o;
    o[0]=f2bf(a[0]); o[1]=f2bf(a[1]); o[2]=f2bf(a[2]); o[3]=f2bf(a[3]);
    o[4]=f2bf(b[0]); o[5]=f2bf(b[1]); o[6]=f2bf(b[2]); o[7]=f2bf(b[3]);
    *(u16x8_t*)(dst + i) = o;
    return;
  }
  if (bid < 6144) {                       // weight transposes (K,N)->(N,K)
    const float* src; unsigned short* dst; float scale = 1.f;
    int Ksz, Nsz, n0, k0;
    if (bid < 4096) {                     // 8x 512x512
      int tt = bid - 2048, z = tt >> 8, w = tt & 255;
      Ksz = 512; Nsz = 512; n0 = (w & 15) * 32; k0 = (w >> 4) * 32;
      switch (z) {
        case 0: src = s0; dst = d0; scale = QSCALE; break;
        case 1: src = s1; dst = d1; break;
        case 2: src = s2; dst = d2; break;
        case 3: src = s3; dst = d3; break;
        case 4: src = s4; dst = d4; scale = QSCALE; break;
        case 5: src = s5; dst = d5; break;
        case 6: src = s6; dst = d6; break;
        default: src = s7; dst = d7; break;
      }
    } else if (bid < 5120) {              // fw1 (512,2048)->(2048,512)
      int tt = bid - 4096;
      src = fw1; dst = w1t; Ksz = 512; Nsz = 2048;
      n0 = (tt & 63) * 32; k0 = (tt >> 6) * 32;
    } else {                              // fw2 (2048,512)->(512,2048)
      int tt = bid - 5120;
      src = fw2; dst = w2t; Ksz = 2048; Nsz = 512;
      n0 = (tt & 15) * 32; k0 = (tt >> 4) * 32;
    }
    int tx = tid & 31, ty = tid >> 5;
#pragma unroll
    for (int i = 0; i < 4; i++)
      t[ty + 8*i][tx] = src[(size_t)(k0 + ty + 8*i) * Nsz + n0 + tx];
    __syncthreads();
#pragma unroll
    for (int i = 0; i < 4; i++)
      dst[(size_t)(n0 + ty + 8*i) * Ksz + k0 + tx] = f2bf(t[tx][ty + 8*i] * scale);
    return;
  }
  {                                       // bias pack
    int i = (bid - 6144) * 256 + tid;
    int seg = i >> 9, off = i & 511;
    switch (seg) {
      case 0: bqkv1[off]        = q1[off] * QSCALE; break;
      case 1: bqkv1[512 + off]  = k1[off]; break;
      case 2: bqkv1[1024 + off] = v1[off]; break;
      case 3: bq2[off]          = q2[off] * QSCALE; break;
      case 4: bkv2[off]         = k2[off]; break;
      default: bkv2[512 + off]  = v2[off]; break;
    }
  }
}

// ---------------- merged bf16 transpose for V1 and V2 ----------------
__global__ void __launch_bounds__(256) vtrans2(const unsigned short* __restrict__ src1, int lds1, int co1,
                                               unsigned short* __restrict__ dst1,
                                               const unsigned short* __restrict__ src2, int lds2, int co2,
                                               unsigned short* __restrict__ dst2, int Skv) {
  __shared__ unsigned short t[64][65];
  int st = blockIdx.x * 64, yy = blockIdx.y;
  const unsigned short* src = yy < 16 ? src1 : src2;
  unsigned short* dst = yy < 16 ? dst1 : dst2;
  int lds_ = yy < 16 ? lds1 : lds2;
  int coloff = yy < 16 ? co1 : co2;
  int bh = yy & 15;
  int b = bh >> 3, h = bh & 7;
  int tid = threadIdx.x;
  const unsigned short* s = src + ((size_t)b * Skv + st) * lds_ + coloff + h * 64;
#pragma unroll
  for (int i = 0; i < 16; i++) {
    int e = i * 256 + tid; int r = e >> 6, d = e & 63;
    t[r][d] = s[(size_t)r * lds_ + d];
  }
  __syncthreads();
  unsigned short* dp = dst + (size_t)bh * 64 * Skv + st;
#pragma unroll
  for (int i = 0; i < 2; i++) {
    int e = i * 256 + tid;
    int d = e >> 3, rc = (e & 7) * 8;
    u16x8_t o;
#pragma unroll
    for (int k = 0; k < 8; k++) o[k] = t[rc + k][d];
    *(u16x8_t*)(dp + (size_t)d * Skv + rc) = o;
  }
}

// ---------------- GEMM core (shared by all variants) ----------------
template <int BM, int BN, int EPI>
__device__ __forceinline__ void gemm_core(const unsigned short* A, int lda,
                                          const unsigned short* Bt, int ldb,
                                          const float* bias, void* Cv, int ldc, int K,
                                          long brow, long bcol, char* ldsA, char* ldsB) {
  constexpr int WM = BM / 2, WN = BN / 2, FM = WM / 16, FN = WN / 16;
  constexpr int ITA = BM * 8 / 256, ITB = BN * 8 / 256;
  constexpr int ABY = BM * 128, BBY = BN * 128;   // bytes per buffer
  const int tid = threadIdx.x;
  const int lane = tid & 63, wave = tid >> 6;
  const int wr = wave >> 1, wc = wave & 1;
  const int l15 = lane & 15, l4 = lane >> 4;

  const unsigned short* ag[ITA]; unsigned int al[ITA];
  const unsigned short* bg[ITB]; unsigned int bl[ITB];
#pragma unroll
  for (int i = 0; i < ITA; i++) {
    int L = tid + 256 * i, row = L >> 3, c = L & 7, g = c ^ (row & 7);
    ag[i] = A + (brow + row) * (long)lda + g * 8;
    al[i] = (unsigned int)L * 16;
  }
#pragma unroll
  for (int i = 0; i < ITB; i++) {
    int L = tid + 256 * i, row = L >> 3, c = L & 7, g = c ^ (row & 7);
    bg[i] = Bt + (bcol + row) * (long)ldb + g * 8;
    bl[i] = (unsigned int)L * 16;
  }

  unsigned int aoff[FM][2], boff[FN][2];
#pragma unroll
  for (int m = 0; m < FM; m++)
#pragma unroll
    for (int kk = 0; kk < 2; kk++) {
      int row = wr * WM + m * 16 + l15;
      aoff[m][kk] = (unsigned int)row * 128 + ((((unsigned)(kk * 4 + l4)) ^ (unsigned)(row & 7)) << 4);
    }
#pragma unroll
  for (int n = 0; n < FN; n++)
#pragma unroll
    for (int kk = 0; kk < 2; kk++) {
      int col = wc * WN + n * 16 + l15;
      boff[n][kk] = (unsigned int)col * 128 + ((((unsigned)(kk * 4 + l4)) ^ (unsigned)(col & 7)) << 4);
    }

  f32x4_t acc[FM][FN] = {};
  const int nt = K >> 6;

#pragma unroll
  for (int i = 0; i < ITA; i++) { gload16(ag[i], ldsA + al[i]); ag[i] += 64; }
#pragma unroll
  for (int i = 0; i < ITB; i++) { gload16(bg[i], ldsB + bl[i]); bg[i] += 64; }
  __syncthreads();

  int cur = 0;
  for (int t = 0; t < nt; ++t) {
    if (t + 1 < nt) {
      unsigned int da = (cur ^ 1) * ABY, db = (cur ^ 1) * BBY;
#pragma unroll
      for (int i = 0; i < ITA; i++) { gload16(ag[i], ldsA + da + al[i]); ag[i] += 64; }
#pragma unroll
      for (int i = 0; i < ITB; i++) { gload16(bg[i], ldsB + db + bl[i]); bg[i] += 64; }
    }
    const char* pa = ldsA + cur * ABY;
    const char* pb = ldsB + cur * BBY;
#pragma unroll
    for (int kk = 0; kk < 2; kk++) {
      bf16x8_t af[FM], bfr[FN];
#pragma unroll
      for (int m = 0; m < FM; m++) af[m] = *(const bf16x8_t*)(pa + aoff[m][kk]);
#pragma unroll
      for (int n = 0; n < FN; n++) bfr[n] = *(const bf16x8_t*)(pb + boff[n][kk]);
#pragma unroll
      for (int m = 0; m < FM; m++)
#pragma unroll
        for (int n = 0; n < FN; n++)
          acc[m][n] = MFMA16(af[m], bfr[n], acc[m][n]);
    }
    __syncthreads();
    cur ^= 1;
  }

#pragma unroll
  for (int m = 0; m < FM; m++)
#pragma unroll
    for (int n = 0; n < FN; n++) {
      long col = bcol + wc * WN + n * 16 + l15;
      float bv = (EPI == 3) ? 0.f : bias[col];
#pragma unroll
      for (int j = 0; j < 4; j++) {
        long row = brow + wr * WM + m * 16 + l4 * 4 + j;
        float v = acc[m][n][j] + bv;
        if (EPI == 1) v = fmaxf(v, 0.f);
        if (EPI == 2) ((float*)Cv)[row * ldc + col] = v;
        else          ((unsigned short*)Cv)[row * ldc + col] = f2bf(v);
      }
    }
}

template <int BM, int BN, int EPI>
__global__ void __launch_bounds__(256) gemm_bt(const unsigned short* __restrict__ A, int lda,
                                               const unsigned short* __restrict__ Bt, int ldb,
                                               const float* __restrict__ bias,
                                               void* __restrict__ Cv, int ldc, int K) {
  __shared__ __align__(16) char ldsA[2 * BM * 128];
  __shared__ __align__(16) char ldsB[2 * BN * 128];
  gemm_core<BM, BN, EPI>(A, lda, Bt, ldb, bias, Cv, ldc, K,
                         (long)blockIdx.x * BM, (long)blockIdx.y * BN, ldsA, ldsB);
}

// merged qkv1 + kv2 GEMM: y<12 -> qkv1 (A=xb), else kv2 (A=eb)
__global__ void __launch_bounds__(256) gemm_qkvkv(const unsigned short* __restrict__ xb,
                                                  const unsigned short* __restrict__ eb,
                                                  const unsigned short* __restrict__ wqkv1t,
                                                  const unsigned short* __restrict__ wkv2t,
                                                  const float* __restrict__ bqkv1,
                                                  const float* __restrict__ bkv2,
                                                  unsigned short* __restrict__ qkv1,
                                                  unsigned short* __restrict__ kv2) {
  __shared__ __align__(16) char ldsA[2 * 64 * 128];
  __shared__ __align__(16) char ldsB[2 * 128 * 128];
  const int y = blockIdx.y;
  if (y < 12)
    gemm_core<64, 128, 0>(xb, DM, wqkv1t, 512, bqkv1, qkv1, 1536, 512,
                          (long)blockIdx.x * 64, (long)y * 128, ldsA, ldsB);
  else
    gemm_core<64, 128, 0>(eb, DM, wkv2t, 512, bkv2, kv2, 1024, 512,
                          (long)blockIdx.x * 64, (long)(y - 12) * 128, ldsA, ldsB);
}

// ---------------- split-K GEMM for ffn2: bf16 partials, no bias ----------------
template <int BM, int BN>
__global__ void __launch_bounds__(256) gemm_btk(const unsigned short* __restrict__ A, int lda,
                                                const unsigned short* __restrict__ Bt, int ldb,
                                                unsigned short* __restrict__ Cp, int ldc, int Kchunk) {
  __shared__ __align__(16) char ldsA[2 * BM * 128];
  __shared__ __align__(16) char ldsB[2 * BN * 128];
  gemm_core<BM, BN, 3>(A + blockIdx.z * Kchunk, lda, Bt + blockIdx.z * Kchunk, ldb, nullptr,
                       Cp + (size_t)blockIdx.z * NT * DM, ldc, Kchunk,
                       (long)blockIdx.x * BM, (long)blockIdx.y * BN, ldsA, ldsB);
}

// ---------------- fused split-KV combine + o-projection GEMM ----------------
template <int C>
__global__ void __launch_bounds__(256) gemm_att_o(const unsigned short* __restrict__ obuf,
                                                  const float* __restrict__ lbuf,
                                                  const unsigned short* __restrict__ Bt,
                                                  const float* __restrict__ bias,
                                                  unsigned short* __restrict__ Cv) {
  constexpr int ABY = 64 * 128, BBY = 64 * 128;
  __shared__ __align__(16) char ldsA[2 * ABY];
  __shared__ __align__(16) char ldsB[2 * BBY];
  const int tid = threadIdx.x;
  const int lane = tid & 63, wave = tid >> 6;
  const int wr = wave >> 1, wc = wave & 1;
  const int l15 = lane & 15, l4 = lane >> 4;
  const long brow = (long)blockIdx.x * 64;
  const long bcol = (long)blockIdx.y * 64;

  unsigned int awr[2];
  size_t obase[2][C];
  const float* lptr[2][C];
#pragma unroll
  for (int i = 0; i < 2; i++) {
    int L = tid + 256 * i;
    int r = L >> 3, cc = L & 7;
    awr[i] = (unsigned int)r * 128 + (((unsigned)cc ^ (unsigned)(r & 7)) << 4);
    long R = brow + r;
    int b = (int)(R >> 11);
    int s = (int)(R & 2047);
    int q64 = s >> 6, rr = s & 63;
#pragma unroll
    for (int c = 0; c < C; c++) {
      size_t blk0 = (size_t)(c * 512 + b * 256 + q64);   // + h*32 added per step
      obase[i][c] = blk0 * 4096 + (size_t)rr * 64 + cc * 8;
      lptr[i][c]  = lbuf + blk0 * 64 + rr;
    }
  }
  const unsigned short* bg[2]; unsigned int bl[2];
#pragma unroll
  for (int i = 0; i < 2; i++) {
    int L = tid + 256 * i, row = L >> 3, c = L & 7, g = c ^ (row & 7);
    bg[i] = Bt + (bcol + row) * 512L + g * 8;
    bl[i] = (unsigned int)L * 16;
  }

  unsigned int aoff[2][2], boff[2][2];
#pragma unroll
  for (int m = 0; m < 2; m++)
#pragma unroll
    for (int kk = 0; kk < 2; kk++) {
      int row = wr * 32 + m * 16 + l15;
      aoff[m][kk] = (unsigned int)row * 128 + ((((unsigned)(kk * 4 + l4)) ^ (unsigned)(row & 7)) << 4);
      int col = wc * 32 + m * 16 + l15;
      boff[m][kk] = (unsigned int)col * 128 + ((((unsigned)(kk * 4 + l4)) ^ (unsigned)(col & 7)) << 4);
    }

  float a8[2][8], inv2[2];
  auto loadA = [&](int h) {
    size_t hoff = (size_t)h * 32 * 4096;
    size_t hlo  = (size_t)h * 32 * 64;
#pragma unroll
    for (int i = 0; i < 2; i++) {
      float s8[8] = {0.f, 0.f, 0.f, 0.f, 0.f, 0.f, 0.f, 0.f};
      float lsum = 0.f;
#pragma unroll
      for (int c = 0; c < C; c++) {
        u16x8_t a = *(const u16x8_t*)(obuf + obase[i][c] + hoff);
        lsum += lptr[i][c][hlo];
#pragma unroll
        for (int k = 0; k < 8; k++) s8[k] += bf2f(a[k]);
      }
      inv2[i] = 1.f / lsum;
#pragma unroll
      for (int k = 0; k < 8; k++) a8[i][k] = s8[k];
    }
  };
  auto writeA = [&](char* dst) {
#pragma unroll
    for (int i = 0; i < 2; i++) {
      u32x4_t w;
      w[0] = cvtpk(a8[i][0] * inv2[i], a8[i][1] * inv2[i]);
      w[1] = cvtpk(a8[i][2] * inv2[i], a8[i][3] * inv2[i]);
      w[2] = cvtpk(a8[i][4] * inv2[i], a8[i][5] * inv2[i]);
      w[3] = cvtpk(a8[i][6] * inv2[i], a8[i][7] * inv2[i]);
      *(u32x4_t*)(dst + awr[i]) = w;
    }
  };

  f32x4_t acc[2][2] = {};

  loadA(0);
#pragma unroll
  for (int i = 0; i < 2; i++) { gload16(bg[i], ldsB + bl[i]); bg[i] += 64; }
  writeA(ldsA);
  __syncthreads();

  int cur = 0;
  for (int t = 0; t < 8; ++t) {
    if (t + 1 < 8) {
      loadA(t + 1);                               // issue combine loads early
      unsigned int db = (cur ^ 1) * BBY;
#pragma unroll
      for (int i = 0; i < 2; i++) { gload16(bg[i], ldsB + db + bl[i]); bg[i] += 64; }
    }
    const char* pa = ldsA + cur * ABY;
    const char* pb = ldsB + cur * BBY;
#pragma unroll
    for (int kk = 0; kk < 2; kk++) {
      bf16x8_t af[2], bfr[2];
#pragma unroll
      for (int m = 0; m < 2; m++) af[m] = *(const bf16x8_t*)(pa + aoff[m][kk]);
#pragma unroll
      for (int n = 0; n < 2; n++) bfr[n] = *(const bf16x8_t*)(pb + boff[n][kk]);
#pragma unroll
      for (int m = 0; m < 2; m++)
#pragma unroll
        for (int n = 0; n < 2; n++)
          acc[m][n] = MFMA16(af[m], bfr[n], acc[m][n]);
    }
    if (t + 1 < 8) writeA(ldsA + (cur ^ 1) * ABY);  // loads landed under MFMA phase
    __syncthreads();
    cur ^= 1;
  }

#pragma unroll
  for (int m = 0; m < 2; m++)
#pragma unroll
    for (int n = 0; n < 2; n++) {
      long col = bcol + wc * 32 + n * 16 + l15;
      float bv = bias[col];
#pragma unroll
      for (int j = 0; j < 4; j++) {
        long row = brow + wr * 32 + m * 16 + l4 * 4 + j;
        Cv[row * DM + col] = f2bf(acc[m][n][j] + bv);
      }
    }
}

// ---------------- flash attention: 8-wave block (128 q-rows), split-KV, no-max, P-in-regs ----------------
// __launch_bounds__(512,8): cap VGPR at 64 -> 4 blocks/CU (32 waves, full occupancy cap).
template <bool CAUSAL, int C>
__global__ void __launch_bounds__(512, 8) attn_part(const unsigned short* __restrict__ Q, int ldq, int qc0,
                                                    const unsigned short* __restrict__ Kb, int ldk, int kc0,
                                                    const unsigned short* __restrict__ Vt,
                                                    unsigned short* __restrict__ obuf,
                                                    float* __restrict__ lbuf, int Skv) {
  __shared__ __align__(16) unsigned short kt[2][4096];
  __shared__ __align__(16) unsigned short vt[2][4096];
  const int qt = blockIdx.x, bh = blockIdx.y, cch = blockIdx.z;
  const int b = bh >> 3, h = bh & 7;
  const int tid = threadIdx.x, wave = tid >> 6, lane = tid & 63;
  const int sub = wave >> 2, wrow = wave & 3;
  const int l15 = lane & 15, l4 = lane >> 4, q7 = l15 & 7;
  const long qrow0 = (long)b * SQ + qt * 128 + sub * 64;
  const long krow0 = (long)b * Skv;
  const unsigned short* vtb = Vt + (size_t)bh * 64 * Skv;
  const int qoff = qc0 + h * 64, koff = kc0 + h * 64;

  const int ntt = CAUSAL ? (2 * qt + 2) : (Skv >> 6);
  const int t0 = (ntt * cch) / C, t1 = (ntt * (cch + 1)) / C;

  bf16x8_t qf[2];
  {
    long qr = qrow0 + wrow * 16 + l15;
    const unsigned short* qp = Q + qr * (long)ldq + qoff + l4 * 8;
    qf[0] = *(const bf16x8_t*)(qp);
    qf[1] = *(const bf16x8_t*)(qp + 32);
  }

  const unsigned short* kg; const unsigned short* vg;
  {
    int sr = tid >> 3, scc = tid & 7;
    int ssc = scc ^ (sr & 7);
    int rk = (sr & 0x23) | ((sr & 0x0C) << 1) | ((sr & 0x10) >> 2);  // tau(sr)
    kg = Kb + (krow0 + t0 * 64 + rk) * (long)ldk + koff + ssc * 8;
    vg = vtb + (size_t)sr * Skv + t0 * 64 + ssc * 8;
  }
  const unsigned int sld = (unsigned int)tid * 16;
  const long kstep = 64 * (long)ldk;

  const unsigned int pbase = (unsigned int)l15 * 128;
  unsigned int xo[2];
  xo[0] = ((unsigned)(l4 ^ q7)) << 4;
  xo[1] = ((unsigned)((4 + l4) ^ q7)) << 4;

  const int qa = qt * 128 + sub * 64 + wrow * 16 + l15;  // global q row
  const int tdiag = qt * 2 + sub;

  f32x4_t of[4] = {};
  float lrow = 0.f;

  if (t0 < t1) {
    gload16(kg, (char*)kt + sld);
    gload16(vg, (char*)vt + sld);
    kg += kstep; vg += 64;
  }

  int cur = 0;
  for (int t = t0; t < t1; ++t) {
    asm volatile("s_waitcnt vmcnt(0)" ::: "memory");   // this wave's stage loads landed
    __builtin_amdgcn_s_barrier();
    if (t + 1 < t1) {
      unsigned int d = (cur ^ 1) * 8192;
      gload16(kg, (char*)kt + d + sld);
      gload16(vg, (char*)vt + d + sld);
      kg += kstep; vg += 64;
    }
    const char* kbp = (const char*)kt + cur * 8192 + pbase;
    const char* vbp = (const char*)vt + cur * 8192 + pbase;

    f32x4_t sf[4] = {};
    __builtin_amdgcn_s_setprio(1);
#pragma unroll
    for (int n = 0; n < 4; n++) {
      bf16x8_t kf0 = *(const bf16x8_t*)(kbp + xo[0] + n * 2048);
      bf16x8_t kf1 = *(const bf16x8_t*)(kbp + xo[1] + n * 2048);
      sf[n] = MFMA16(kf0, qf[0], sf[n]);
      sf[n] = MFMA16(kf1, qf[1], sf[n]);
    }
    __builtin_amdgcn_s_setprio(0);
    if (CAUSAL && t >= tdiag) {
      int base = (t << 6) + 8 * l4 - qa;   // mask if base + kbn + j > 0
#pragma unroll
      for (int n = 0; n < 4; n++) {
        int kbn = 32 * (n >> 1) + 4 * (n & 1);
#pragma unroll
        for (int j = 0; j < 4; j++)
          if (base + kbn + j > 0) sf[n][j] = -1e30f;
      }
    }
#pragma unroll
    for (int n = 0; n < 4; n++)
#pragma unroll
      for (int j = 0; j < 4; j++) sf[n][j] = exp2fast(sf[n][j]);
    f32x4_t rv = (sf[0] + sf[1]) + (sf[2] + sf[3]);
    lrow += (rv[0] + rv[1]) + (rv[2] + rv[3]);

    union { unsigned int u[4]; bf16x8_t v; } pa0, pa1;
    pa0.u[0] = cvtpk(sf[0][0], sf[0][1]); pa0.u[1] = cvtpk(sf[0][2], sf[0][3]);
    pa0.u[2] = cvtpk(sf[1][0], sf[1][1]); pa0.u[3] = cvtpk(sf[1][2], sf[1][3]);
    pa1.u[0] = cvtpk(sf[2][0], sf[2][1]); pa1.u[1] = cvtpk(sf[2][2], sf[2][3]);
    pa1.u[2] = cvtpk(sf[3][0], sf[3][1]); pa1.u[3] = cvtpk(sf[3][2], sf[3][3]);

    __builtin_amdgcn_s_setprio(1);
#pragma unroll
    for (int n2 = 0; n2 < 4; n2++) {
      bf16x8_t vf0 = *(const bf16x8_t*)(vbp + xo[0] + n2 * 2048);
      bf16x8_t vf1 = *(const bf16x8_t*)(vbp + xo[1] + n2 * 2048);
      of[n2] = MFMA16(pa0.v, vf0, of[n2]);
      of[n2] = MFMA16(pa1.v, vf1, of[n2]);
    }
    __builtin_amdgcn_s_setprio(0);
    cur ^= 1;
  }
  const int blk = (cch * 16 + bh) * 32 + qt * 2 + sub;
  unsigned short* ob = obuf + (size_t)blk * 4096;
#pragma unroll
  for (int j = 0; j < 4; j++) {
    int row = wrow * 16 + l4 * 4 + j;
#pragma unroll
    for (int n2 = 0; n2 < 4; n2++)
      ob[row * 64 + n2 * 16 + l15] = f2bf(of[n2][j]);
  }
  lrow += __shfl_xor(lrow, 16);
  lrow += __shfl_xor(lrow, 32);
  if (l4 == 0) lbuf[(size_t)blk * 64 + wrow * 16 + l15] = lrow;
}

// ---------------- residual + LayerNorm: a (bf16) + residual (fp32 or bf16), bf16 out ----------------
template <bool RF32>
__global__ void __launch_bounds__(256) ln_kernel(const unsigned short* __restrict__ a, const void* __restrict__ rv,
                                                 const float* __restrict__ g, const float* __restrict__ be,
                                                 unsigned short* __restrict__ outb) {
  const int wave = threadIdx.x >> 6, lane = threadIdx.x & 63;
  const long row = (long)blockIdx.x * 4 + wave;
  const int off = lane * 8;
  u16x8_t av = *(const u16x8_t*)(a + row * DM + off);
  float rr[8];
  if (RF32) {
    const float* r = (const float*)rv;
    f32x4_t r0 = *(const f32x4_t*)(r + row * DM + off);
    f32x4_t r1 = *(const f32x4_t*)(r + row * DM + off + 4);
#pragma unroll
    for (int k = 0; k < 4; k++) { rr[k] = r0[k]; rr[k + 4] = r1[k]; }
  } else {
    u16x8_t r8 = *(const u16x8_t*)((const unsigned short*)rv + row * DM + off);
#pragma unroll
    for (int k = 0; k < 8; k++) rr[k] = bf2f(r8[k]);
  }
  float v[8];
  float s = 0.f, ss = 0.f;
#pragma unroll
  for (int k = 0; k < 8; k++) {
    v[k] = bf2f(av[k]) + rr[k];
    s += v[k]; ss += v[k] * v[k];
  }
#pragma unroll
  for (int d = 1; d < 64; d <<= 1) { s += __shfl_xor(s, d); ss += __shfl_xor(ss, d); }
  float mean = s * (1.f / 512.f);
  float var = ss * (1.f / 512.f) - mean * mean;
  float rstd = rsqrtf(var + 1e-6f);
  f32x4_t g0 = *(const f32x4_t*)(g + off), g1 = *(const f32x4_t*)(g + off + 4);
  f32x4_t b0 = *(const f32x4_t*)(be + off), b1 = *(const f32x4_t*)(be + off + 4);
  u16x8_t ob;
#pragma unroll
  for (int k = 0; k < 4; k++) {
    ob[k]     = f2bf((v[k] - mean) * rstd * g0[k] + b0[k]);
    ob[k + 4] = f2bf((v[k + 4] - mean) * rstd * g1[k] + b1[k]);
  }
  *(u16x8_t*)(outb + row * DM + off) = ob;
}

// ---------------- fused: sum 2 bf16 split-K partials + bias + bf16 residual + LayerNorm -> fp32 ----------------
__global__ void __launch_bounds__(256) ln_ffn2(const unsigned short* __restrict__ pbase,
                                               const float* __restrict__ bias,
                                               const unsigned short* __restrict__ resid,
                                               const float* __restrict__ g, const float* __restrict__ be,
                                               float* __restrict__ outf) {
  const int wave = threadIdx.x >> 6, lane = threadIdx.x & 63;
  const long row = (long)blockIdx.x * 4 + wave;
  const size_t stride = (size_t)NT * DM;
  const int off = lane * 8;
  u16x8_t p0 = *(const u16x8_t*)(pbase + row * DM + off);
  u16x8_t p1 = *(const u16x8_t*)(pbase + stride + row * DM + off);
  u16x8_t r8 = *(const u16x8_t*)(resid + row * DM + off);
  f32x4_t b0 = *(const f32x4_t*)(bias + off), b1 = *(const f32x4_t*)(bias + off + 4);
  float v[8];
  float s = 0.f, ss = 0.f;
#pragma unroll
  for (int k = 0; k < 8; k++) {
    v[k] = bf2f(p0[k]) + bf2f(p1[k]) + bf2f(r8[k]) + (k < 4 ? b0[k] : b1[k - 4]);
    s += v[k]; ss += v[k] * v[k];
  }
#pragma unroll
  for (int d = 1; d < 64; d <<= 1) { s += __shfl_xor(s, d); ss += __shfl_xor(ss, d); }
  float mean = s * (1.f / 512.f);
  float var = ss * (1.f / 512.f) - mean * mean;
  float rstd = rsqrtf(var + 1e-6f);
  f32x4_t g0 = *(const f32x4_t*)(g + off), g1 = *(const f32x4_t*)(g + off + 4);
  f32x4_t be0 = *(const f32x4_t*)(be + off), be1 = *(const f32x4_t*)(be + off + 4);
  f32x4_t o0, o1;
#pragma unroll
  for (int k = 0; k < 4; k++) {
    o0[k] = (v[k] - mean) * rstd * g0[k] + be0[k];
    o1[k] = (v[k + 4] - mean) * rstd * g1[k] + be1[k];
  }
  *(f32x4_t*)(outf + row * DM + off) = o0;
  *(f32x4_t*)(outf + row * DM + off + 4) = o1;
}

extern "C" void kernel_launch(void* const* d_in, const int* in_sizes, int n_in,
                              void* d_out, int out_size, void* d_ws, size_t ws_size,
                              hipStream_t stream) {
  (void)in_sizes; (void)n_in; (void)out_size;
  const float* x   = (const float*)d_in[0];
  const float* enc = (const float*)d_in[1];
  const float* w1q = (const float*)d_in[4];  const float* b1q = (const float*)d_in[5];
  const float* w1k = (const float*)d_in[6];  const float* b1k = (const float*)d_in[7];
  const float* w1v = (const float*)d_in[8];  const float* b1v = (const float*)d_in[9];
  const float* w1o = (const float*)d_in[10]; const float* b1o = (const float*)d_in[11];
  const float* w2q = (const float*)d_in[12]; const float* b2q = (const float*)d_in[13];
  const float* w2k = (const float*)d_in[14]; const float* b2k = (const float*)d_in[15];
  const float* w2v = (const float*)d_in[16]; const float* b2v = (const float*)d_in[17];
  const float* w2o = (const float*)d_in[18]; const float* b2o = (const float*)d_in[19];
  const float* fw1 = (const float*)d_in[20]; const float* fb1 = (const float*)d_in[21];
  const float* fw2 = (const float*)d_in[22]; const float* fb2 = (const float*)d_in[23];
  const float* g1  = (const float*)d_in[24]; const float* be1 = (const float*)d_in[25];
  const float* g2  = (const float*)d_in[26]; const float* be2 = (const float*)d_in[27];
  const float* g3  = (const float*)d_in[28]; const float* be3 = (const float*)d_in[29];

  char* ws = (char*)d_ws;
  size_t off = 0;
  auto alloc = [&](size_t bytes) -> void* {
    void* p = ws + off;
    off = (off + bytes + 255) & ~(size_t)255;
    return p;
  };
  unsigned short* xb     = (unsigned short*)alloc((size_t)NT * DM * 2);
  unsigned short* eb     = (unsigned short*)alloc((size_t)NT * DM * 2);
  unsigned short* wqkv1t = (unsigned short*)alloc((size_t)1536 * 512 * 2);
  unsigned short* wo1t   = (unsigned short*)alloc((size_t)512 * 512 * 2);
  unsigned short* wq2t   = (unsigned short*)alloc((size_t)512 * 512 * 2);
  unsigned short* wkv2t  = (unsigned short*)alloc((size_t)1024 * 512 * 2);
  unsigned short* wo2t   = (unsigned short*)alloc((size_t)512 * 512 * 2);
  unsigned short* w1t    = (unsigned short*)alloc((size_t)2048 * 512 * 2);
  unsigned short* w2t    = (unsigned short*)alloc((size_t)512 * 2048 * 2);
  float* bqkv1 = (float*)alloc(1536 * 4);
  float* bq2s  = (float*)alloc(512 * 4);
  float* bkv2  = (float*)alloc(1024 * 4);
  unsigned short* qkv1  = (unsigned short*)alloc((size_t)NT * 1536 * 2);
  unsigned short* vt1   = (unsigned short*)alloc((size_t)16 * 64 * SQ * 2);
  unsigned short* vt2   = (unsigned short*)alloc((size_t)16 * 64 * SQ * 2);
  unsigned short* tmpb  = (unsigned short*)alloc((size_t)NT * DM * 2);
  unsigned short* out1b = (unsigned short*)alloc((size_t)NT * DM * 2);
  unsigned short* kv2   = (unsigned short*)alloc((size_t)NT * 1024 * 2);
  unsigned short* out2b = (unsigned short*)alloc((size_t)NT * DM * 2);
  unsigned short* hbuf  = (unsigned short*)alloc((size_t)NT * 2048 * 2);
  // dedicated scratch
  unsigned short* obuf = (unsigned short*)alloc((size_t)2048 * 4096 * 2);  // 16MB (C<=4)
  float*          lbuf = (float*)alloc((size_t)2048 * 64 * 4);             // 512KB
  unsigned short* pbuf = (unsigned short*)alloc((size_t)2 * NT * DM * 2);  // 8MB bf16 partials
  // reuse dead buffers
  unsigned short* q2 = xb;     // xb dead after merged QKV GEMM
  if (off > ws_size) return;  // workspace too small -> loud validation failure

  // ---- fused preprocessing (1 launch) ----
  prep_all<<<6156, 256, 0, stream>>>(
      x, xb, enc, eb,
      w1q, w1k, w1v, w1o, w2q, w2k, w2v, w2o,
      wqkv1t, wqkv1t + 512 * 512, wqkv1t + 1024 * 512, wo1t,
      wq2t, wkv2t, wkv2t + 512 * 512, wo2t,
      fw1, w1t, fw2, w2t,
      b1q, b1k, b1v, b2q, b2k, b2v, bqkv1, bq2s, bkv2);

  // ---- merged qkv1 + kv2 GEMM, merged V transposes ----
  gemm_qkvkv<<<dim3(64, 20), 256, 0, stream>>>(xb, eb, wqkv1t, wkv2t, bqkv1, bkv2, qkv1, kv2);
  vtrans2<<<dim3(32, 32), 256, 0, stream>>>(qkv1, 1536, 1024, vt1, kv2, 1024, 512, vt2, SQ);

  // ---- self-attention block ----
  attn_part<true, 4><<<dim3(16, 16, 4), 512, 0, stream>>>(qkv1, 1536, 0, qkv1, 1536, 512, vt1, obuf, lbuf, SQ);
  gemm_att_o<4><<<dim3(64, 8), 256, 0, stream>>>(obuf, lbuf, wo1t, b1o, tmpb);
  ln_kernel<true><<<1024, 256, 0, stream>>>(tmpb, x, g1, be1, out1b);

  // ---- cross-attention block ----
  gemm_bt<64, 64, 0><<<dim3(64, 8), 256, 0, stream>>>(out1b, DM, wq2t, 512, bq2s, q2, DM, 512);
  attn_part<false, 2><<<dim3(16, 16, 2), 512, 0, stream>>>(q2, DM, 0, kv2, 1024, 0, vt2, obuf, lbuf, SQ);
  gemm_att_o<2><<<dim3(64, 8), 256, 0, stream>>>(obuf, lbuf, wo2t, b2o, tmpb);
  ln_kernel<false><<<1024, 256, 0, stream>>>(tmpb, out1b, g2, be2, out2b);

  // ---- FFN block ----
  gemm_bt<128, 128, 1><<<dim3(32, 16), 256, 0, stream>>>(out2b, DM, w1t, 512, fb1, hbuf, 2048, 512);
  gemm_btk<64, 128><<<dim3(64, 4, 2), 256, 0, stream>>>(hbuf, 2048, w2t, 2048, pbuf, DM, 1024);
  ln_ffn2<<<1024, 256, 0, stream>>>(pbuf, fb2, out2b, g3, be3, (float*)d_out);
}

// Round 15
// 154.456 us; speedup vs baseline: 1.0311x; 1.0311x over previous
//
#include <hip/hip_runtime.h>
#include <stdint.h>

#define NT 4096      // B*S rows of activations
#define SQ 2048      // sequence length (queries; SE is also 2048)
#define DM 512       // model dim

typedef __attribute__((ext_vector_type(4))) float          f32x4_t;
typedef __attribute__((ext_vector_type(8))) short          bf16x8_t;
typedef __attribute__((ext_vector_type(8))) unsigned short u16x8_t;
typedef __attribute__((ext_vector_type(4))) unsigned int   u32x4_t;

#define QSCALE 0.18033688011112042f   // 0.125 * log2(e): softmax via 2^x

__device__ __forceinline__ unsigned short f2bf(float f) {
  unsigned int u = __float_as_uint(f);
  u = u + 0x7FFFu + ((u >> 16) & 1u);   // round-to-nearest-even
  return (unsigned short)(u >> 16);
}
__device__ __forceinline__ float bf2f(unsigned short u) {
  return __uint_as_float((unsigned int)u << 16);
}
__device__ __forceinline__ unsigned int cvtpk(float lo, float hi) {
  unsigned int r;
  asm("v_cvt_pk_bf16_f32 %0, %1, %2" : "=v"(r) : "v"(lo), "v"(hi));
  return r;
}
__device__ __forceinline__ float exp2fast(float x) {
  float r;
  asm("v_exp_f32 %0, %1" : "=v"(r) : "v"(x));   // 2^x
  return r;
}

__device__ __forceinline__ void gload16(const void* g, void* l) {
  __builtin_amdgcn_global_load_lds(
      (__attribute__((address_space(1))) void*)(g),
      (__attribute__((address_space(3))) void*)(l), 16, 0, 0);
}

#define MFMA16(A, B, C) __builtin_amdgcn_mfma_f32_16x16x32_bf16((A), (B), (C), 0, 0, 0)

// ---------------- fused preprocessing: cvt x/enc + 10 weight transposes + bias pack ----------------
__global__ void __launch_bounds__(256) prep_all(
    const float* xs, unsigned short* xd, const float* es, unsigned short* ed,
    const float* s0, const float* s1, const float* s2, const float* s3,
    const float* s4, const float* s5, const float* s6, const float* s7,
    unsigned short* d0, unsigned short* d1, unsigned short* d2, unsigned short* d3,
    unsigned short* d4, unsigned short* d5, unsigned short* d6, unsigned short* d7,
    const float* fw1, unsigned short* w1t, const float* fw2, unsigned short* w2t,
    const float* q1, const float* k1, const float* v1,
    const float* q2, const float* k2, const float* v2,
    float* bqkv1, float* bq2, float* bkv2) {
  __shared__ float t[32][33];
  const int bid = blockIdx.x, tid = threadIdx.x;
  if (bid < 2048) {                       // fp32 -> bf16 conversions
    const float* src = bid < 1024 ? xs : es;
    unsigned short* dst = bid < 1024 ? xd : ed;
    int i = ((bid & 1023) * 256 + tid) * 8;
    f32x4_t a = *(const f32x4_t*)(src + i);
    f32x4_t b = *(const f32x4_t*)(src + i + 4);
    u16x8_t o;
    o[0]=f2bf(a[0]); o[1]=f2bf(a[1]); o[2]=f2bf(a[2]); o[3]=f2bf(a[3]);
    o[4]=f2bf(b[0]); o[5]=f2bf(b[1]); o[6]=f2bf(b[2]); o[7]=f2bf(b[3]);
    *(u16x8_t*)(dst + i) = o;
    return;
  }
  if (bid < 6144) {                       // weight transposes (K,N)->(N,K)
    const float* src; unsigned short* dst; float scale = 1.f;
    int Ksz, Nsz, n0, k0;
    if (bid < 4096) {                     // 8x 512x512
      int tt = bid - 2048, z = tt >> 8, w = tt & 255;
      Ksz = 512; Nsz = 512; n0 = (w & 15) * 32; k0 = (w >> 4) * 32;
      switch (z) {
        case 0: src = s0; dst = d0; scale = QSCALE; break;
        case 1: src = s1; dst = d1; break;
        case 2: src = s2; dst = d2; break;
        case 3: src = s3; dst = d3; break;
        case 4: src = s4; dst = d4; scale = QSCALE; break;
        case 5: src = s5; dst = d5; break;
        case 6: src = s6; dst = d6; break;
        default: src = s7; dst = d7; break;
      }
    } else if (bid < 5120) {              // fw1 (512,2048)->(2048,512)
      int tt = bid - 4096;
      src = fw1; dst = w1t; Ksz = 512; Nsz = 2048;
      n0 = (tt & 63) * 32; k0 = (tt >> 6) * 32;
    } else {                              // fw2 (2048,512)->(512,2048)
      int tt = bid - 5120;
      src = fw2; dst = w2t; Ksz = 2048; Nsz = 512;
      n0 = (tt & 15) * 32; k0 = (tt >> 4) * 32;
    }
    int tx = tid & 31, ty = tid >> 5;
#pragma unroll
    for (int i = 0; i < 4; i++)
      t[ty + 8*i][tx] = src[(size_t)(k0 + ty + 8*i) * Nsz + n0 + tx];
    __syncthreads();
#pragma unroll
    for (int i = 0; i < 4; i++)
      dst[(size_t)(n0 + ty + 8*i) * Ksz + k0 + tx] = f2bf(t[tx][ty + 8*i] * scale);
    return;
  }
  {                                       // bias pack
    int i = (bid - 6144) * 256 + tid;
    int seg = i >> 9, off = i & 511;
    switch (seg) {
      case 0: bqkv1[off]        = q1[off] * QSCALE; break;
      case 1: bqkv1[512 + off]  = k1[off]; break;
      case 2: bqkv1[1024 + off] = v1[off]; break;
      case 3: bq2[off]          = q2[off] * QSCALE; break;
      case 4: bkv2[off]         = k2[off]; break;
      default: bkv2[512 + off]  = v2[off]; break;
    }
  }
}

// ---------------- merged bf16 transpose for V1 and V2 ----------------
__global__ void __launch_bounds__(256) vtrans2(const unsigned short* __restrict__ src1, int lds1, int co1,
                                               unsigned short* __restrict__ dst1,
                                               const unsigned short* __restrict__ src2, int lds2, int co2,
                                               unsigned short* __restrict__ dst2, int Skv) {
  __shared__ unsigned short t[64][65];
  int st = blockIdx.x * 64, yy = blockIdx.y;
  const unsigned short* src = yy < 16 ? src1 : src2;
  unsigned short* dst = yy < 16 ? dst1 : dst2;
  int lds_ = yy < 16 ? lds1 : lds2;
  int coloff = yy < 16 ? co1 : co2;
  int bh = yy & 15;
  int b = bh >> 3, h = bh & 7;
  int tid = threadIdx.x;
  const unsigned short* s = src + ((size_t)b * Skv + st) * lds_ + coloff + h * 64;
#pragma unroll
  for (int i = 0; i < 16; i++) {
    int e = i * 256 + tid; int r = e >> 6, d = e & 63;
    t[r][d] = s[(size_t)r * lds_ + d];
  }
  __syncthreads();
  unsigned short* dp = dst + (size_t)bh * 64 * Skv + st;
#pragma unroll
  for (int i = 0; i < 2; i++) {
    int e = i * 256 + tid;
    int d = e >> 3, rc = (e & 7) * 8;
    u16x8_t o;
#pragma unroll
    for (int k = 0; k < 8; k++) o[k] = t[rc + k][d];
    *(u16x8_t*)(dp + (size_t)d * Skv + rc) = o;
  }
}

// ---------------- GEMM core (shared by all variants) ----------------
template <int BM, int BN, int EPI>
__device__ __forceinline__ void gemm_core(const unsigned short* A, int lda,
                                          const unsigned short* Bt, int ldb,
                                          const float* bias, void* Cv, int ldc, int K,
                                          long brow, long bcol, char* ldsA, char* ldsB) {
  constexpr int WM = BM / 2, WN = BN / 2, FM = WM / 16, FN = WN / 16;
  constexpr int ITA = BM * 8 / 256, ITB = BN * 8 / 256;
  constexpr int ABY = BM * 128, BBY = BN * 128;   // bytes per buffer
  const int tid = threadIdx.x;
  const int lane = tid & 63, wave = tid >> 6;
  const int wr = wave >> 1, wc = wave & 1;
  const int l15 = lane & 15, l4 = lane >> 4;

  const unsigned short* ag[ITA]; unsigned int al[ITA];
  const unsigned short* bg[ITB]; unsigned int bl[ITB];
#pragma unroll
  for (int i = 0; i < ITA; i++) {
    int L = tid + 256 * i, row = L >> 3, c = L & 7, g = c ^ (row & 7);
    ag[i] = A + (brow + row) * (long)lda + g * 8;
    al[i] = (unsigned int)L * 16;
  }
#pragma unroll
  for (int i = 0; i < ITB; i++) {
    int L = tid + 256 * i, row = L >> 3, c = L & 7, g = c ^ (row & 7);
    bg[i] = Bt + (bcol + row) * (long)ldb + g * 8;
    bl[i] = (unsigned int)L * 16;
  }

  unsigned int aoff[FM][2], boff[FN][2];
#pragma unroll
  for (int m = 0; m < FM; m++)
#pragma unroll
    for (int kk = 0; kk < 2; kk++) {
      int row = wr * WM + m * 16 + l15;
      aoff[m][kk] = (unsigned int)row * 128 + ((((unsigned)(kk * 4 + l4)) ^ (unsigned)(row & 7)) << 4);
    }
#pragma unroll
  for (int n = 0; n < FN; n++)
#pragma unroll
    for (int kk = 0; kk < 2; kk++) {
      int col = wc * WN + n * 16 + l15;
      boff[n][kk] = (unsigned int)col * 128 + ((((unsigned)(kk * 4 + l4)) ^ (unsigned)(col & 7)) << 4);
    }

  f32x4_t acc[FM][FN] = {};
  const int nt = K >> 6;

#pragma unroll
  for (int i = 0; i < ITA; i++) { gload16(ag[i], ldsA + al[i]); ag[i] += 64; }
#pragma unroll
  for (int i = 0; i < ITB; i++) { gload16(bg[i], ldsB + bl[i]); bg[i] += 64; }
  __syncthreads();

  int cur = 0;
  for (int t = 0; t < nt; ++t) {
    if (t + 1 < nt) {
      unsigned int da = (cur ^ 1) * ABY, db = (cur ^ 1) * BBY;
#pragma unroll
      for (int i = 0; i < ITA; i++) { gload16(ag[i], ldsA + da + al[i]); ag[i] += 64; }
#pragma unroll
      for (int i = 0; i < ITB; i++) { gload16(bg[i], ldsB + db + bl[i]); bg[i] += 64; }
    }
    const char* pa = ldsA + cur * ABY;
    const char* pb = ldsB + cur * BBY;
#pragma unroll
    for (int kk = 0; kk < 2; kk++) {
      bf16x8_t af[FM], bfr[FN];
#pragma unroll
      for (int m = 0; m < FM; m++) af[m] = *(const bf16x8_t*)(pa + aoff[m][kk]);
#pragma unroll
      for (int n = 0; n < FN; n++) bfr[n] = *(const bf16x8_t*)(pb + boff[n][kk]);
#pragma unroll
      for (int m = 0; m < FM; m++)
#pragma unroll
        for (int n = 0; n < FN; n++)
          acc[m][n] = MFMA16(af[m], bfr[n], acc[m][n]);
    }
    __syncthreads();
    cur ^= 1;
  }

#pragma unroll
  for (int m = 0; m < FM; m++)
#pragma unroll
    for (int n = 0; n < FN; n++) {
      long col = bcol + wc * WN + n * 16 + l15;
      float bv = (EPI == 3) ? 0.f : bias[col];
#pragma unroll
      for (int j = 0; j < 4; j++) {
        long row = brow + wr * WM + m * 16 + l4 * 4 + j;
        float v = acc[m][n][j] + bv;
        if (EPI == 1) v = fmaxf(v, 0.f);
        if (EPI == 2) ((float*)Cv)[row * ldc + col] = v;
        else          ((unsigned short*)Cv)[row * ldc + col] = f2bf(v);
      }
    }
}

template <int BM, int BN, int EPI>
__global__ void __launch_bounds__(256) gemm_bt(const unsigned short* __restrict__ A, int lda,
                                               const unsigned short* __restrict__ Bt, int ldb,
                                               const float* __restrict__ bias,
                                               void* __restrict__ Cv, int ldc, int K) {
  __shared__ __align__(16) char ldsA[2 * BM * 128];
  __shared__ __align__(16) char ldsB[2 * BN * 128];
  gemm_core<BM, BN, EPI>(A, lda, Bt, ldb, bias, Cv, ldc, K,
                         (long)blockIdx.x * BM, (long)blockIdx.y * BN, ldsA, ldsB);
}

// merged qkv1 + kv2 GEMM: y<12 -> qkv1 (A=xb), else kv2 (A=eb)
__global__ void __launch_bounds__(256) gemm_qkvkv(const unsigned short* __restrict__ xb,
                                                  const unsigned short* __restrict__ eb,
                                                  const unsigned short* __restrict__ wqkv1t,
                                                  const unsigned short* __restrict__ wkv2t,
                                                  const float* __restrict__ bqkv1,
                                                  const float* __restrict__ bkv2,
                                                  unsigned short* __restrict__ qkv1,
                                                  unsigned short* __restrict__ kv2) {
  __shared__ __align__(16) char ldsA[2 * 64 * 128];
  __shared__ __align__(16) char ldsB[2 * 128 * 128];
  const int y = blockIdx.y;
  if (y < 12)
    gemm_core<64, 128, 0>(xb, DM, wqkv1t, 512, bqkv1, qkv1, 1536, 512,
                          (long)blockIdx.x * 64, (long)y * 128, ldsA, ldsB);
  else
    gemm_core<64, 128, 0>(eb, DM, wkv2t, 512, bkv2, kv2, 1024, 512,
                          (long)blockIdx.x * 64, (long)(y - 12) * 128, ldsA, ldsB);
}

// ---------------- split-K GEMM for ffn2: bf16 partials, no bias ----------------
template <int BM, int BN>
__global__ void __launch_bounds__(256) gemm_btk(const unsigned short* __restrict__ A, int lda,
                                                const unsigned short* __restrict__ Bt, int ldb,
                                                unsigned short* __restrict__ Cp, int ldc, int Kchunk) {
  __shared__ __align__(16) char ldsA[2 * BM * 128];
  __shared__ __align__(16) char ldsB[2 * BN * 128];
  gemm_core<BM, BN, 3>(A + blockIdx.z * Kchunk, lda, Bt + blockIdx.z * Kchunk, ldb, nullptr,
                       Cp + (size_t)blockIdx.z * NT * DM, ldc, Kchunk,
                       (long)blockIdx.x * BM, (long)blockIdx.y * BN, ldsA, ldsB);
}

// ---------------- fused split-KV combine + o-projection GEMM ----------------
template <int C>
__global__ void __launch_bounds__(256) gemm_att_o(const unsigned short* __restrict__ obuf,
                                                  const float* __restrict__ lbuf,
                                                  const unsigned short* __restrict__ Bt,
                                                  const float* __restrict__ bias,
                                                  unsigned short* __restrict__ Cv) {
  constexpr int ABY = 64 * 128, BBY = 64 * 128;
  __shared__ __align__(16) char ldsA[2 * ABY];
  __shared__ __align__(16) char ldsB[2 * BBY];
  const int tid = threadIdx.x;
  const int lane = tid & 63, wave = tid >> 6;
  const int wr = wave >> 1, wc = wave & 1;
  const int l15 = lane & 15, l4 = lane >> 4;
  const long brow = (long)blockIdx.x * 64;
  const long bcol = (long)blockIdx.y * 64;

  unsigned int awr[2];
  size_t obase[2][C];
  const float* lptr[2][C];
#pragma unroll
  for (int i = 0; i < 2; i++) {
    int L = tid + 256 * i;
    int r = L >> 3, cc = L & 7;
    awr[i] = (unsigned int)r * 128 + (((unsigned)cc ^ (unsigned)(r & 7)) << 4);
    long R = brow + r;
    int b = (int)(R >> 11);
    int s = (int)(R & 2047);
    int q64 = s >> 6, rr = s & 63;
#pragma unroll
    for (int c = 0; c < C; c++) {
      size_t blk0 = (size_t)(c * 512 + b * 256 + q64);   // + h*32 added per step
      obase[i][c] = blk0 * 4096 + (size_t)rr * 64 + cc * 8;
      lptr[i][c]  = lbuf + blk0 * 64 + rr;
    }
  }
  const unsigned short* bg[2]; unsigned int bl[2];
#pragma unroll
  for (int i = 0; i < 2; i++) {
    int L = tid + 256 * i, row = L >> 3, c = L & 7, g = c ^ (row & 7);
    bg[i] = Bt + (bcol + row) * 512L + g * 8;
    bl[i] = (unsigned int)L * 16;
  }

  unsigned int aoff[2][2], boff[2][2];
#pragma unroll
  for (int m = 0; m < 2; m++)
#pragma unroll
    for (int kk = 0; kk < 2; kk++) {
      int row = wr * 32 + m * 16 + l15;
      aoff[m][kk] = (unsigned int)row * 128 + ((((unsigned)(kk * 4 + l4)) ^ (unsigned)(row & 7)) << 4);
      int col = wc * 32 + m * 16 + l15;
      boff[m][kk] = (unsigned int)col * 128 + ((((unsigned)(kk * 4 + l4)) ^ (unsigned)(col & 7)) << 4);
    }

  float a8[2][8], inv2[2];
  auto loadA = [&](int h) {
    size_t hoff = (size_t)h * 32 * 4096;
    size_t hlo  = (size_t)h * 32 * 64;
#pragma unroll
    for (int i = 0; i < 2; i++) {
      float s8[8] = {0.f, 0.f, 0.f, 0.f, 0.f, 0.f, 0.f, 0.f};
      float lsum = 0.f;
#pragma unroll
      for (int c = 0; c < C; c++) {
        u16x8_t a = *(const u16x8_t*)(obuf + obase[i][c] + hoff);
        lsum += lptr[i][c][hlo];
#pragma unroll
        for (int k = 0; k < 8; k++) s8[k] += bf2f(a[k]);
      }
      inv2[i] = 1.f / lsum;
#pragma unroll
      for (int k = 0; k < 8; k++) a8[i][k] = s8[k];
    }
  };
  auto writeA = [&](char* dst) {
#pragma unroll
    for (int i = 0; i < 2; i++) {
      u32x4_t w;
      w[0] = cvtpk(a8[i][0] * inv2[i], a8[i][1] * inv2[i]);
      w[1] = cvtpk(a8[i][2] * inv2[i], a8[i][3] * inv2[i]);
      w[2] = cvtpk(a8[i][4] * inv2[i], a8[i][5] * inv2[i]);
      w[3] = cvtpk(a8[i][6] * inv2[i], a8[i][7] * inv2[i]);
      *(u32x4_t*)(dst + awr[i]) = w;
    }
  };

  f32x4_t acc[2][2] = {};

  loadA(0);
#pragma unroll
  for (int i = 0; i < 2; i++) { gload16(bg[i], ldsB + bl[i]); bg[i] += 64; }
  writeA(ldsA);
  __syncthreads();

  int cur = 0;
  for (int t = 0; t < 8; ++t) {
    if (t + 1 < 8) {
      loadA(t + 1);                               // issue combine loads early
      unsigned int db = (cur ^ 1) * BBY;
#pragma unroll
      for (int i = 0; i < 2; i++) { gload16(bg[i], ldsB + db + bl[i]); bg[i] += 64; }
    }
    const char* pa = ldsA + cur * ABY;
    const char* pb = ldsB + cur * BBY;
#pragma unroll
    for (int kk = 0; kk < 2; kk++) {
      bf16x8_t af[2], bfr[2];
#pragma unroll
      for (int m = 0; m < 2; m++) af[m] = *(const bf16x8_t*)(pa + aoff[m][kk]);
#pragma unroll
      for (int n = 0; n < 2; n++) bfr[n] = *(const bf16x8_t*)(pb + boff[n][kk]);
#pragma unroll
      for (int m = 0; m < 2; m++)
#pragma unroll
        for (int n = 0; n < 2; n++)
          acc[m][n] = MFMA16(af[m], bfr[n], acc[m][n]);
    }
    if (t + 1 < 8) writeA(ldsA + (cur ^ 1) * ABY);  // loads landed under MFMA phase
    __syncthreads();
    cur ^= 1;
  }

#pragma unroll
  for (int m = 0; m < 2; m++)
#pragma unroll
    for (int n = 0; n < 2; n++) {
      long col = bcol + wc * 32 + n * 16 + l15;
      float bv = bias[col];
#pragma unroll
      for (int j = 0; j < 4; j++) {
        long row = brow + wr * 32 + m * 16 + l4 * 4 + j;
        Cv[row * DM + col] = f2bf(acc[m][n][j] + bv);
      }
    }
}

// ---------------- flash attention: 8-wave block (128 q-rows), split-KV, no-max, P-in-regs ----------------
// (512,6): 3 blocks/CU is this kernel's verified optimum; (512,8) spills (r14 regression).
template <bool CAUSAL, int C>
__global__ void __launch_bounds__(512, 6) attn_part(const unsigned short* __restrict__ Q, int ldq, int qc0,
                                                    const unsigned short* __restrict__ Kb, int ldk, int kc0,
                                                    const unsigned short* __restrict__ Vt,
                                                    unsigned short* __restrict__ obuf,
                                                    float* __restrict__ lbuf, int Skv) {
  __shared__ __align__(16) unsigned short kt[2][4096];
  __shared__ __align__(16) unsigned short vt[2][4096];
  const int qt = blockIdx.x, bh = blockIdx.y, cch = blockIdx.z;
  const int b = bh >> 3, h = bh & 7;
  const int tid = threadIdx.x, wave = tid >> 6, lane = tid & 63;
  const int sub = wave >> 2, wrow = wave & 3;
  const int l15 = lane & 15, l4 = lane >> 4, q7 = l15 & 7;
  const long qrow0 = (long)b * SQ + qt * 128 + sub * 64;
  const long krow0 = (long)b * Skv;
  const unsigned short* vtb = Vt + (size_t)bh * 64 * Skv;
  const int qoff = qc0 + h * 64, koff = kc0 + h * 64;

  const int ntt = CAUSAL ? (2 * qt + 2) : (Skv >> 6);
  const int t0 = (ntt * cch) / C, t1 = (ntt * (cch + 1)) / C;

  bf16x8_t qf[2];
  {
    long qr = qrow0 + wrow * 16 + l15;
    const unsigned short* qp = Q + qr * (long)ldq + qoff + l4 * 8;
    qf[0] = *(const bf16x8_t*)(qp);
    qf[1] = *(const bf16x8_t*)(qp + 32);
  }

  const unsigned short* kg; const unsigned short* vg;
  {
    int sr = tid >> 3, scc = tid & 7;
    int ssc = scc ^ (sr & 7);
    int rk = (sr & 0x23) | ((sr & 0x0C) << 1) | ((sr & 0x10) >> 2);  // tau(sr)
    kg = Kb + (krow0 + t0 * 64 + rk) * (long)ldk + koff + ssc * 8;
    vg = vtb + (size_t)sr * Skv + t0 * 64 + ssc * 8;
  }
  const unsigned int sld = (unsigned int)tid * 16;
  const long kstep = 64 * (long)ldk;

  const unsigned int pbase = (unsigned int)l15 * 128;
  unsigned int xo[2];
  xo[0] = ((unsigned)(l4 ^ q7)) << 4;
  xo[1] = ((unsigned)((4 + l4) ^ q7)) << 4;

  const int qa = qt * 128 + sub * 64 + wrow * 16 + l15;  // global q row
  const int tdiag = qt * 2 + sub;

  f32x4_t of[4] = {};
  float lrow = 0.f;

  if (t0 < t1) {
    gload16(kg, (char*)kt + sld);
    gload16(vg, (char*)vt + sld);
    kg += kstep; vg += 64;
  }

  int cur = 0;
  for (int t = t0; t < t1; ++t) {
    asm volatile("s_waitcnt vmcnt(0)" ::: "memory");   // this wave's stage loads landed
    __builtin_amdgcn_s_barrier();
    if (t + 1 < t1) {
      unsigned int d = (cur ^ 1) * 8192;
      gload16(kg, (char*)kt + d + sld);
      gload16(vg, (char*)vt + d + sld);
      kg += kstep; vg += 64;
    }
    const char* kbp = (const char*)kt + cur * 8192 + pbase;
    const char* vbp = (const char*)vt + cur * 8192 + pbase;

    f32x4_t sf[4] = {};
    __builtin_amdgcn_s_setprio(1);
#pragma unroll
    for (int n = 0; n < 4; n++) {
      bf16x8_t kf0 = *(const bf16x8_t*)(kbp + xo[0] + n * 2048);
      bf16x8_t kf1 = *(const bf16x8_t*)(kbp + xo[1] + n * 2048);
      sf[n] = MFMA16(kf0, qf[0], sf[n]);
      sf[n] = MFMA16(kf1, qf[1], sf[n]);
    }
    __builtin_amdgcn_s_setprio(0);
    if (CAUSAL && t >= tdiag) {
      int base = (t << 6) + 8 * l4 - qa;   // mask if base + kbn + j > 0
#pragma unroll
      for (int n = 0; n < 4; n++) {
        int kbn = 32 * (n >> 1) + 4 * (n & 1);
#pragma unroll
        for (int j = 0; j < 4; j++)
          if (base + kbn + j > 0) sf[n][j] = -1e30f;
      }
    }
#pragma unroll
    for (int n = 0; n < 4; n++)
#pragma unroll
      for (int j = 0; j < 4; j++) sf[n][j] = exp2fast(sf[n][j]);
    f32x4_t rv = (sf[0] + sf[1]) + (sf[2] + sf[3]);
    lrow += (rv[0] + rv[1]) + (rv[2] + rv[3]);

    union { unsigned int u[4]; bf16x8_t v; } pa0, pa1;
    pa0.u[0] = cvtpk(sf[0][0], sf[0][1]); pa0.u[1] = cvtpk(sf[0][2], sf[0][3]);
    pa0.u[2] = cvtpk(sf[1][0], sf[1][1]); pa0.u[3] = cvtpk(sf[1][2], sf[1][3]);
    pa1.u[0] = cvtpk(sf[2][0], sf[2][1]); pa1.u[1] = cvtpk(sf[2][2], sf[2][3]);
    pa1.u[2] = cvtpk(sf[3][0], sf[3][1]); pa1.u[3] = cvtpk(sf[3][2], sf[3][3]);

    __builtin_amdgcn_s_setprio(1);
#pragma unroll
    for (int n2 = 0; n2 < 4; n2++) {
      bf16x8_t vf0 = *(const bf16x8_t*)(vbp + xo[0] + n2 * 2048);
      bf16x8_t vf1 = *(const bf16x8_t*)(vbp + xo[1] + n2 * 2048);
      of[n2] = MFMA16(pa0.v, vf0, of[n2]);
      of[n2] = MFMA16(pa1.v, vf1, of[n2]);
    }
    __builtin_amdgcn_s_setprio(0);
    cur ^= 1;
  }
  const int blk = (cch * 16 + bh) * 32 + qt * 2 + sub;
  unsigned short* ob = obuf + (size_t)blk * 4096;
#pragma unroll
  for (int j = 0; j < 4; j++) {
    int row = wrow * 16 + l4 * 4 + j;
#pragma unroll
    for (int n2 = 0; n2 < 4; n2++)
      ob[row * 64 + n2 * 16 + l15] = f2bf(of[n2][j]);
  }
  lrow += __shfl_xor(lrow, 16);
  lrow += __shfl_xor(lrow, 32);
  if (l4 == 0) lbuf[(size_t)blk * 64 + wrow * 16 + l15] = lrow;
}

// ---------------- residual + LayerNorm: a (bf16) + residual (fp32 or bf16), bf16 out ----------------
template <bool RF32>
__global__ void __launch_bounds__(256) ln_kernel(const unsigned short* __restrict__ a, const void* __restrict__ rv,
                                                 const float* __restrict__ g, const float* __restrict__ be,
                                                 unsigned short* __restrict__ outb) {
  const int wave = threadIdx.x >> 6, lane = threadIdx.x & 63;
  const long row = (long)blockIdx.x * 4 + wave;
  const int off = lane * 8;
  u16x8_t av = *(const u16x8_t*)(a + row * DM + off);
  float rr[8];
  if (RF32) {
    const float* r = (const float*)rv;
    f32x4_t r0 = *(const f32x4_t*)(r + row * DM + off);
    f32x4_t r1 = *(const f32x4_t*)(r + row * DM + off + 4);
#pragma unroll
    for (int k = 0; k < 4; k++) { rr[k] = r0[k]; rr[k + 4] = r1[k]; }
  } else {
    u16x8_t r8 = *(const u16x8_t*)((const unsigned short*)rv + row * DM + off);
#pragma unroll
    for (int k = 0; k < 8; k++) rr[k] = bf2f(r8[k]);
  }
  float v[8];
  float s = 0.f, ss = 0.f;
#pragma unroll
  for (int k = 0; k < 8; k++) {
    v[k] = bf2f(av[k]) + rr[k];
    s += v[k]; ss += v[k] * v[k];
  }
#pragma unroll
  for (int d = 1; d < 64; d <<= 1) { s += __shfl_xor(s, d); ss += __shfl_xor(ss, d); }
  float mean = s * (1.f / 512.f);
  float var = ss * (1.f / 512.f) - mean * mean;
  float rstd = rsqrtf(var + 1e-6f);
  f32x4_t g0 = *(const f32x4_t*)(g + off), g1 = *(const f32x4_t*)(g + off + 4);
  f32x4_t b0 = *(const f32x4_t*)(be + off), b1 = *(const f32x4_t*)(be + off + 4);
  u16x8_t ob;
#pragma unroll
  for (int k = 0; k < 4; k++) {
    ob[k]     = f2bf((v[k] - mean) * rstd * g0[k] + b0[k]);
    ob[k + 4] = f2bf((v[k + 4] - mean) * rstd * g1[k] + b1[k]);
  }
  *(u16x8_t*)(outb + row * DM + off) = ob;
}

// ---------------- fused: sum 2 bf16 split-K partials + bias + bf16 residual + LayerNorm -> fp32 ----------------
__global__ void __launch_bounds__(256) ln_ffn2(const unsigned short* __restrict__ pbase,
                                               const float* __restrict__ bias,
                                               const unsigned short* __restrict__ resid,
                                               const float* __restrict__ g, const float* __restrict__ be,
                                               float* __restrict__ outf) {
  const int wave = threadIdx.x >> 6, lane = threadIdx.x & 63;
  const long row = (long)blockIdx.x * 4 + wave;
  const size_t stride = (size_t)NT * DM;
  const int off = lane * 8;
  u16x8_t p0 = *(const u16x8_t*)(pbase + row * DM + off);
  u16x8_t p1 = *(const u16x8_t*)(pbase + stride + row * DM + off);
  u16x8_t r8 = *(const u16x8_t*)(resid + row * DM + off);
  f32x4_t b0 = *(const f32x4_t*)(bias + off), b1 = *(const f32x4_t*)(bias + off + 4);
  float v[8];
  float s = 0.f, ss = 0.f;
#pragma unroll
  for (int k = 0; k < 8; k++) {
    v[k] = bf2f(p0[k]) + bf2f(p1[k]) + bf2f(r8[k]) + (k < 4 ? b0[k] : b1[k - 4]);
    s += v[k]; ss += v[k] * v[k];
  }
#pragma unroll
  for (int d = 1; d < 64; d <<= 1) { s += __shfl_xor(s, d); ss += __shfl_xor(ss, d); }
  float mean = s * (1.f / 512.f);
  float var = ss * (1.f / 512.f) - mean * mean;
  float rstd = rsqrtf(var + 1e-6f);
  f32x4_t g0 = *(const f32x4_t*)(g + off), g1 = *(const f32x4_t*)(g + off + 4);
  f32x4_t be0 = *(const f32x4_t*)(be + off), be1 = *(const f32x4_t*)(be + off + 4);
  f32x4_t o0, o1;
#pragma unroll
  for (int k = 0; k < 4; k++) {
    o0[k] = (v[k] - mean) * rstd * g0[k] + be0[k];
    o1[k] = (v[k + 4] - mean) * rstd * g1[k] + be1[k];
  }
  *(f32x4_t*)(outf + row * DM + off) = o0;
  *(f32x4_t*)(outf + row * DM + off + 4) = o1;
}

extern "C" void kernel_launch(void* const* d_in, const int* in_sizes, int n_in,
                              void* d_out, int out_size, void* d_ws, size_t ws_size,
                              hipStream_t stream) {
  (void)in_sizes; (void)n_in; (void)out_size;
  const float* x   = (const float*)d_in[0];
  const float* enc = (const float*)d_in[1];
  const float* w1q = (const float*)d_in[4];  const float* b1q = (const float*)d_in[5];
  const float* w1k = (const float*)d_in[6];  const float* b1k = (const float*)d_in[7];
  const float* w1v = (const float*)d_in[8];  const float* b1v = (const float*)d_in[9];
  const float* w1o = (const float*)d_in[10]; const float* b1o = (const float*)d_in[11];
  const float* w2q = (const float*)d_in[12]; const float* b2q = (const float*)d_in[13];
  const float* w2k = (const float*)d_in[14]; const float* b2k = (const float*)d_in[15];
  const float* w2v = (const float*)d_in[16]; const float* b2v = (const float*)d_in[17];
  const float* w2o = (const float*)d_in[18]; const float* b2o = (const float*)d_in[19];
  const float* fw1 = (const float*)d_in[20]; const float* fb1 = (const float*)d_in[21];
  const float* fw2 = (const float*)d_in[22]; const float* fb2 = (const float*)d_in[23];
  const float* g1  = (const float*)d_in[24]; const float* be1 = (const float*)d_in[25];
  const float* g2  = (const float*)d_in[26]; const float* be2 = (const float*)d_in[27];
  const float* g3  = (const float*)d_in[28]; const float* be3 = (const float*)d_in[29];

  char* ws = (char*)d_ws;
  size_t off = 0;
  auto alloc = [&](size_t bytes) -> void* {
    void* p = ws + off;
    off = (off + bytes + 255) & ~(size_t)255;
    return p;
  };
  unsigned short* xb     = (unsigned short*)alloc((size_t)NT * DM * 2);
  unsigned short* eb     = (unsigned short*)alloc((size_t)NT * DM * 2);
  unsigned short* wqkv1t = (unsigned short*)alloc((size_t)1536 * 512 * 2);
  unsigned short* wo1t   = (unsigned short*)alloc((size_t)512 * 512 * 2);
  unsigned short* wq2t   = (unsigned short*)alloc((size_t)512 * 512 * 2);
  unsigned short* wkv2t  = (unsigned short*)alloc((size_t)1024 * 512 * 2);
  unsigned short* wo2t   = (unsigned short*)alloc((size_t)512 * 512 * 2);
  unsigned short* w1t    = (unsigned short*)alloc((size_t)2048 * 512 * 2);
  unsigned short* w2t    = (unsigned short*)alloc((size_t)512 * 2048 * 2);
  float* bqkv1 = (float*)alloc(1536 * 4);
  float* bq2s  = (float*)alloc(512 * 4);
  float* bkv2  = (float*)alloc(1024 * 4);
  unsigned short* qkv1  = (unsigned short*)alloc((size_t)NT * 1536 * 2);
  unsigned short* vt1   = (unsigned short*)alloc((size_t)16 * 64 * SQ * 2);
  unsigned short* vt2   = (unsigned short*)alloc((size_t)16 * 64 * SQ * 2);
  unsigned short* tmpb  = (unsigned short*)alloc((size_t)NT * DM * 2);
  unsigned short* out1b = (unsigned short*)alloc((size_t)NT * DM * 2);
  unsigned short* kv2   = (unsigned short*)alloc((size_t)NT * 1024 * 2);
  unsigned short* out2b = (unsigned short*)alloc((size_t)NT * DM * 2);
  unsigned short* hbuf  = (unsigned short*)alloc((size_t)NT * 2048 * 2);
  // dedicated scratch
  unsigned short* obuf = (unsigned short*)alloc((size_t)1536 * 4096 * 2);  // 12MB (C<=3)
  float*          lbuf = (float*)alloc((size_t)1536 * 64 * 4);             // 384KB
  unsigned short* pbuf = (unsigned short*)alloc((size_t)2 * NT * DM * 2);  // 8MB bf16 partials
  // reuse dead buffers
  unsigned short* q2 = xb;     // xb dead after merged QKV GEMM
  if (off > ws_size) return;  // workspace too small -> loud validation failure

  // ---- fused preprocessing (1 launch) ----
  prep_all<<<6156, 256, 0, stream>>>(
      x, xb, enc, eb,
      w1q, w1k, w1v, w1o, w2q, w2k, w2v, w2o,
      wqkv1t, wqkv1t + 512 * 512, wqkv1t + 1024 * 512, wo1t,
      wq2t, wkv2t, wkv2t + 512 * 512, wo2t,
      fw1, w1t, fw2, w2t,
      b1q, b1k, b1v, b2q, b2k, b2v, bqkv1, bq2s, bkv2);

  // ---- merged qkv1 + kv2 GEMM, merged V transposes ----
  gemm_qkvkv<<<dim3(64, 20), 256, 0, stream>>>(xb, eb, wqkv1t, wkv2t, bqkv1, bkv2, qkv1, kv2);
  vtrans2<<<dim3(32, 32), 256, 0, stream>>>(qkv1, 1536, 1024, vt1, kv2, 1024, 512, vt2, SQ);

  // ---- self-attention block ----
  attn_part<true, 3><<<dim3(16, 16, 3), 512, 0, stream>>>(qkv1, 1536, 0, qkv1, 1536, 512, vt1, obuf, lbuf, SQ);
  gemm_att_o<3><<<dim3(64, 8), 256, 0, stream>>>(obuf, lbuf, wo1t, b1o, tmpb);
  ln_kernel<true><<<1024, 256, 0, stream>>>(tmpb, x, g1, be1, out1b);

  // ---- cross-attention block ----
  gemm_bt<64, 64, 0><<<dim3(64, 8), 256, 0, stream>>>(out1b, DM, wq2t, 512, bq2s, q2, DM, 512);
  attn_part<false, 2><<<dim3(16, 16, 2), 512, 0, stream>>>(q2, DM, 0, kv2, 1024, 0, vt2, obuf, lbuf, SQ);
  gemm_att_o<2><<<dim3(64, 8), 256, 0, stream>>>(obuf, lbuf, wo2t, b2o, tmpb);
  ln_kernel<false><<<1024, 256, 0, stream>>>(tmpb, out1b, g2, be2, out2b);

  // ---- FFN block ----
  gemm_bt<128, 128, 1><<<dim3(32, 16), 256, 0, stream>>>(out2b, DM, w1t, 512, fb1, hbuf, 2048, 512);
  gemm_btk<64, 128><<<dim3(64, 4, 2), 256, 0, stream>>>(hbuf, 2048, w2t, 2048, pbuf, DM, 1024);
  ln_ffn2<<<1024, 256, 0, stream>>>(pbuf, fb2, out2b, g3, be3, (float*)d_out);
}

// Round 16
// 148.929 us; speedup vs baseline: 1.0694x; 1.0371x over previous
//
#include <hip/hip_runtime.h>
#include <stdint.h>

#define NT 4096      // B*S rows of activations
#define SQ 2048      // sequence length (queries; SE is also 2048)
#define DM 512       // model dim

typedef __attribute__((ext_vector_type(4))) float          f32x4_t;
typedef __attribute__((ext_vector_type(8))) short          bf16x8_t;
typedef __attribute__((ext_vector_type(8))) unsigned short u16x8_t;
typedef __attribute__((ext_vector_type(4))) unsigned int   u32x4_t;

#define QSCALE 0.18033688011112042f   // 0.125 * log2(e): softmax via 2^x

__device__ __forceinline__ unsigned short f2bf(float f) {
  unsigned int u = __float_as_uint(f);
  u = u + 0x7FFFu + ((u >> 16) & 1u);   // round-to-nearest-even
  return (unsigned short)(u >> 16);
}
__device__ __forceinline__ float bf2f(unsigned short u) {
  return __uint_as_float((unsigned int)u << 16);
}
__device__ __forceinline__ unsigned int cvtpk(float lo, float hi) {
  unsigned int r;
  asm("v_cvt_pk_bf16_f32 %0, %1, %2" : "=v"(r) : "v"(lo), "v"(hi));
  return r;
}
__device__ __forceinline__ float exp2fast(float x) {
  float r;
  asm("v_exp_f32 %0, %1" : "=v"(r) : "v"(x));   // 2^x
  return r;
}

__device__ __forceinline__ void gload16(const void* g, void* l) {
  __builtin_amdgcn_global_load_lds(
      (__attribute__((address_space(1))) void*)(g),
      (__attribute__((address_space(3))) void*)(l), 16, 0, 0);
}

#define MFMA16(A, B, C) __builtin_amdgcn_mfma_f32_16x16x32_bf16((A), (B), (C), 0, 0, 0)

// ---------------- fused preprocessing: cvt x/enc + 10 weight transposes + bias pack ----------------
__global__ void __launch_bounds__(256) prep_all(
    const float* xs, unsigned short* xd, const float* es, unsigned short* ed,
    const float* s0, const float* s1, const float* s2, const float* s3,
    const float* s4, const float* s5, const float* s6, const float* s7,
    unsigned short* d0, unsigned short* d1, unsigned short* d2, unsigned short* d3,
    unsigned short* d4, unsigned short* d5, unsigned short* d6, unsigned short* d7,
    const float* fw1, unsigned short* w1t, const float* fw2, unsigned short* w2t,
    const float* q1, const float* k1, const float* v1,
    const float* q2, const float* k2, const float* v2,
    float* bqkv1, float* bq2, float* bkv2) {
  __shared__ float t[32][33];
  const int bid = blockIdx.x, tid = threadIdx.x;
  if (bid < 2048) {                       // fp32 -> bf16 conversions
    const float* src = bid < 1024 ? xs : es;
    unsigned short* dst = bid < 1024 ? xd : ed;
    int i = ((bid & 1023) * 256 + tid) * 8;
    f32x4_t a = *(const f32x4_t*)(src + i);
    f32x4_t b = *(const f32x4_t*)(src + i + 4);
    u16x8_t o;
    o[0]=f2bf(a[0]); o[1]=f2bf(a[1]); o[2]=f2bf(a[2]); o[3]=f2bf(a[3]);
    o[4]=f2bf(b[0]); o[5]=f2bf(b[1]); o[6]=f2bf(b[2]); o[7]=f2bf(b[3]);
    *(u16x8_t*)(dst + i) = o;
    return;
  }
  if (bid < 6144) {                       // weight transposes (K,N)->(N,K)
    const float* src; unsigned short* dst; float scale = 1.f;
    int Ksz, Nsz, n0, k0;
    if (bid < 4096) {                     // 8x 512x512
      int tt = bid - 2048, z = tt >> 8, w = tt & 255;
      Ksz = 512; Nsz = 512; n0 = (w & 15) * 32; k0 = (w >> 4) * 32;
      switch (z) {
        case 0: src = s0; dst = d0; scale = QSCALE; break;
        case 1: src = s1; dst = d1; break;
        case 2: src = s2; dst = d2; break;
        case 3: src = s3; dst = d3; break;
        case 4: src = s4; dst = d4; scale = QSCALE; break;
        case 5: src = s5; dst = d5; break;
        case 6: src = s6; dst = d6; break;
        default: src = s7; dst = d7; break;
      }
    } else if (bid < 5120) {              // fw1 (512,2048)->(2048,512)
      int tt = bid - 4096;
      src = fw1; dst = w1t; Ksz = 512; Nsz = 2048;
      n0 = (tt & 63) * 32; k0 = (tt >> 6) * 32;
    } else {                              // fw2 (2048,512)->(512,2048)
      int tt = bid - 5120;
      src = fw2; dst = w2t; Ksz = 2048; Nsz = 512;
      n0 = (tt & 15) * 32; k0 = (tt >> 4) * 32;
    }
    int tx = tid & 31, ty = tid >> 5;
#pragma unroll
    for (int i = 0; i < 4; i++)
      t[ty + 8*i][tx] = src[(size_t)(k0 + ty + 8*i) * Nsz + n0 + tx];
    __syncthreads();
#pragma unroll
    for (int i = 0; i < 4; i++)
      dst[(size_t)(n0 + ty + 8*i) * Ksz + k0 + tx] = f2bf(t[tx][ty + 8*i] * scale);
    return;
  }
  {                                       // bias pack
    int i = (bid - 6144) * 256 + tid;
    int seg = i >> 9, off = i & 511;
    switch (seg) {
      case 0: bqkv1[off]        = q1[off] * QSCALE; break;
      case 1: bqkv1[512 + off]  = k1[off]; break;
      case 2: bqkv1[1024 + off] = v1[off]; break;
      case 3: bq2[off]          = q2[off] * QSCALE; break;
      case 4: bkv2[off]         = k2[off]; break;
      default: bkv2[512 + off]  = v2[off]; break;
    }
  }
}

// ---------------- GEMM core (shared by all variants) ----------------
// EPI: 0 bf16 out | 1 bf16 relu | 2 fp32 out | 3 bf16 no-bias | 4 V-transpose-out
// EPI==4 (BM=64,BN=128 only): Cv = vt base for (batch,head0) + local row offset;
// writes vt[(head0 + c>>6)][d=c&63][s] via LDS transpose (aliases ldsB).
template <int BM, int BN, int EPI>
__device__ __forceinline__ void gemm_core(const unsigned short* A, int lda,
                                          const unsigned short* Bt, int ldb,
                                          const float* bias, void* Cv, int ldc, int K,
                                          long brow, long bcol, char* ldsA, char* ldsB) {
  constexpr int WM = BM / 2, WN = BN / 2, FM = WM / 16, FN = WN / 16;
  constexpr int ITA = BM * 8 / 256, ITB = BN * 8 / 256;
  constexpr int ABY = BM * 128, BBY = BN * 128;   // bytes per buffer
  const int tid = threadIdx.x;
  const int lane = tid & 63, wave = tid >> 6;
  const int wr = wave >> 1, wc = wave & 1;
  const int l15 = lane & 15, l4 = lane >> 4;

  const unsigned short* ag[ITA]; unsigned int al[ITA];
  const unsigned short* bg[ITB]; unsigned int bl[ITB];
#pragma unroll
  for (int i = 0; i < ITA; i++) {
    int L = tid + 256 * i, row = L >> 3, c = L & 7, g = c ^ (row & 7);
    ag[i] = A + (brow + row) * (long)lda + g * 8;
    al[i] = (unsigned int)L * 16;
  }
#pragma unroll
  for (int i = 0; i < ITB; i++) {
    int L = tid + 256 * i, row = L >> 3, c = L & 7, g = c ^ (row & 7);
    bg[i] = Bt + (bcol + row) * (long)ldb + g * 8;
    bl[i] = (unsigned int)L * 16;
  }

  unsigned int aoff[FM][2], boff[FN][2];
#pragma unroll
  for (int m = 0; m < FM; m++)
#pragma unroll
    for (int kk = 0; kk < 2; kk++) {
      int row = wr * WM + m * 16 + l15;
      aoff[m][kk] = (unsigned int)row * 128 + ((((unsigned)(kk * 4 + l4)) ^ (unsigned)(row & 7)) << 4);
    }
#pragma unroll
  for (int n = 0; n < FN; n++)
#pragma unroll
    for (int kk = 0; kk < 2; kk++) {
      int col = wc * WN + n * 16 + l15;
      boff[n][kk] = (unsigned int)col * 128 + ((((unsigned)(kk * 4 + l4)) ^ (unsigned)(col & 7)) << 4);
    }

  f32x4_t acc[FM][FN] = {};
  const int nt = K >> 6;

#pragma unroll
  for (int i = 0; i < ITA; i++) { gload16(ag[i], ldsA + al[i]); ag[i] += 64; }
#pragma unroll
  for (int i = 0; i < ITB; i++) { gload16(bg[i], ldsB + bl[i]); bg[i] += 64; }
  __syncthreads();

  int cur = 0;
  for (int t = 0; t < nt; ++t) {
    if (t + 1 < nt) {
      unsigned int da = (cur ^ 1) * ABY, db = (cur ^ 1) * BBY;
#pragma unroll
      for (int i = 0; i < ITA; i++) { gload16(ag[i], ldsA + da + al[i]); ag[i] += 64; }
#pragma unroll
      for (int i = 0; i < ITB; i++) { gload16(bg[i], ldsB + db + bl[i]); bg[i] += 64; }
    }
    const char* pa = ldsA + cur * ABY;
    const char* pb = ldsB + cur * BBY;
#pragma unroll
    for (int kk = 0; kk < 2; kk++) {
      bf16x8_t af[FM], bfr[FN];
#pragma unroll
      for (int m = 0; m < FM; m++) af[m] = *(const bf16x8_t*)(pa + aoff[m][kk]);
#pragma unroll
      for (int n = 0; n < FN; n++) bfr[n] = *(const bf16x8_t*)(pb + boff[n][kk]);
#pragma unroll
      for (int m = 0; m < FM; m++)
#pragma unroll
        for (int n = 0; n < FN; n++)
          acc[m][n] = MFMA16(af[m], bfr[n], acc[m][n]);
    }
    __syncthreads();
    cur ^= 1;
  }

  if (EPI == 4) {
    // transpose epilogue: acc -> ldsT[col][row] (bias applied), then coalesced vt write
    unsigned short* ldsT = (unsigned short*)ldsB;   // dead after K-loop (last barrier passed)
#pragma unroll
    for (int m = 0; m < FM; m++)
#pragma unroll
      for (int n = 0; n < FN; n++) {
        int col = wc * WN + n * 16 + l15;
        float bv = bias[bcol + col];
#pragma unroll
        for (int j = 0; j < 4; j++) {
          int row = wr * WM + m * 16 + l4 * 4 + j;
          ldsT[col * 72 + row] = f2bf(acc[m][n][j] + bv);
        }
      }
    __syncthreads();
    unsigned short* vout = (unsigned short*)Cv;
#pragma unroll
    for (int it = 0; it < 4; it++) {
      int e = it * 2048 + tid * 8;          // 0..8191 over 128 cols x 64 rows
      int c = e >> 6, sl = e & 63;
      u16x8_t o = *(const u16x8_t*)(ldsT + c * 72 + sl);
      *(u16x8_t*)(vout + ((size_t)(c >> 6) << 17) + (size_t)(c & 63) * 2048 + sl) = o;
    }
    return;
  }

#pragma unroll
  for (int m = 0; m < FM; m++)
#pragma unroll
    for (int n = 0; n < FN; n++) {
      long col = bcol + wc * WN + n * 16 + l15;
      float bv = (EPI == 3) ? 0.f : bias[col];
#pragma unroll
      for (int j = 0; j < 4; j++) {
        long row = brow + wr * WM + m * 16 + l4 * 4 + j;
        float v = acc[m][n][j] + bv;
        if (EPI == 1) v = fmaxf(v, 0.f);
        if (EPI == 2) ((float*)Cv)[row * ldc + col] = v;
        else          ((unsigned short*)Cv)[row * ldc + col] = f2bf(v);
      }
    }
}

template <int BM, int BN, int EPI>
__global__ void __launch_bounds__(256) gemm_bt(const unsigned short* __restrict__ A, int lda,
                                               const unsigned short* __restrict__ Bt, int ldb,
                                               const float* __restrict__ bias,
                                               void* __restrict__ Cv, int ldc, int K) {
  __shared__ __align__(16) char ldsA[2 * BM * 128];
  __shared__ __align__(16) char ldsB[2 * BN * 128];
  gemm_core<BM, BN, EPI>(A, lda, Bt, ldb, bias, Cv, ldc, K,
                         (long)blockIdx.x * BM, (long)blockIdx.y * BN, ldsA, ldsB);
}

// merged qkv1 + kv2 GEMM with fused V transpose:
//   y<8:   qkv1 Q/K tiles (normal)   | y 8..11:  qkv1 V tiles -> vt1 (transposed)
//   y 12..15: kv2 K tiles (normal)   | y 16..19: kv2 V tiles -> vt2 (transposed)
__global__ void __launch_bounds__(256) gemm_qkvkv(const unsigned short* __restrict__ xb,
                                                  const unsigned short* __restrict__ eb,
                                                  const unsigned short* __restrict__ wqkv1t,
                                                  const unsigned short* __restrict__ wkv2t,
                                                  const float* __restrict__ bqkv1,
                                                  const float* __restrict__ bkv2,
                                                  unsigned short* __restrict__ qkv1,
                                                  unsigned short* __restrict__ kv2,
                                                  unsigned short* __restrict__ vt1,
                                                  unsigned short* __restrict__ vt2) {
  __shared__ __align__(16) char ldsA[2 * 64 * 128];
  __shared__ __align__(16) char ldsB[2 * 128 * 128];
  const int y = blockIdx.y;
  const long brow = (long)blockIdx.x * 64;
  const int b = (int)(brow >> 11);
  if (y < 8) {
    gemm_core<64, 128, 0>(xb, DM, wqkv1t, 512, bqkv1, qkv1, 1536, 512,
                          brow, (long)y * 128, ldsA, ldsB);
  } else if (y < 12) {
    int head0 = (y - 8) * 2;
    unsigned short* vbase = vt1 + ((size_t)(b * 8 + head0) << 17) + (brow & 2047);
    gemm_core<64, 128, 4>(xb, DM, wqkv1t, 512, bqkv1, vbase, 0, 512,
                          brow, (long)y * 128, ldsA, ldsB);
  } else if (y < 16) {
    gemm_core<64, 128, 0>(eb, DM, wkv2t, 512, bkv2, kv2, 1024, 512,
                          brow, (long)(y - 12) * 128, ldsA, ldsB);
  } else {
    int head0 = (y - 16) * 2;
    unsigned short* vbase = vt2 + ((size_t)(b * 8 + head0) << 17) + (brow & 2047);
    gemm_core<64, 128, 4>(eb, DM, wkv2t, 512, bkv2, vbase, 0, 512,
                          brow, (long)(y - 12) * 128, ldsA, ldsB);
  }
}

// ---------------- split-K GEMM for ffn2: bf16 partials, no bias ----------------
template <int BM, int BN>
__global__ void __launch_bounds__(256) gemm_btk(const unsigned short* __restrict__ A, int lda,
                                                const unsigned short* __restrict__ Bt, int ldb,
                                                unsigned short* __restrict__ Cp, int ldc, int Kchunk) {
  __shared__ __align__(16) char ldsA[2 * BM * 128];
  __shared__ __align__(16) char ldsB[2 * BN * 128];
  gemm_core<BM, BN, 3>(A + blockIdx.z * Kchunk, lda, Bt + blockIdx.z * Kchunk, ldb, nullptr,
                       Cp + (size_t)blockIdx.z * NT * DM, ldc, Kchunk,
                       (long)blockIdx.x * BM, (long)blockIdx.y * BN, ldsA, ldsB);
}

// ---------------- fused split-KV combine + o-projection GEMM ----------------
template <int C>
__global__ void __launch_bounds__(256) gemm_att_o(const unsigned short* __restrict__ obuf,
                                                  const float* __restrict__ lbuf,
                                                  const unsigned short* __restrict__ Bt,
                                                  const float* __restrict__ bias,
                                                  unsigned short* __restrict__ Cv) {
  constexpr int ABY = 64 * 128, BBY = 64 * 128;
  __shared__ __align__(16) char ldsA[2 * ABY];
  __shared__ __align__(16) char ldsB[2 * BBY];
  const int tid = threadIdx.x;
  const int lane = tid & 63, wave = tid >> 6;
  const int wr = wave >> 1, wc = wave & 1;
  const int l15 = lane & 15, l4 = lane >> 4;
  const long brow = (long)blockIdx.x * 64;
  const long bcol = (long)blockIdx.y * 64;

  unsigned int awr[2];
  size_t obase[2][C];
  const float* lptr[2][C];
#pragma unroll
  for (int i = 0; i < 2; i++) {
    int L = tid + 256 * i;
    int r = L >> 3, cc = L & 7;
    awr[i] = (unsigned int)r * 128 + (((unsigned)cc ^ (unsigned)(r & 7)) << 4);
    long R = brow + r;
    int b = (int)(R >> 11);
    int s = (int)(R & 2047);
    int q64 = s >> 6, rr = s & 63;
#pragma unroll
    for (int c = 0; c < C; c++) {
      size_t blk0 = (size_t)(c * 512 + b * 256 + q64);   // + h*32 added per step
      obase[i][c] = blk0 * 4096 + (size_t)rr * 64 + cc * 8;
      lptr[i][c]  = lbuf + blk0 * 64 + rr;
    }
  }
  const unsigned short* bg[2]; unsigned int bl[2];
#pragma unroll
  for (int i = 0; i < 2; i++) {
    int L = tid + 256 * i, row = L >> 3, c = L & 7, g = c ^ (row & 7);
    bg[i] = Bt + (bcol + row) * 512L + g * 8;
    bl[i] = (unsigned int)L * 16;
  }

  unsigned int aoff[2][2], boff[2][2];
#pragma unroll
  for (int m = 0; m < 2; m++)
#pragma unroll
    for (int kk = 0; kk < 2; kk++) {
      int row = wr * 32 + m * 16 + l15;
      aoff[m][kk] = (unsigned int)row * 128 + ((((unsigned)(kk * 4 + l4)) ^ (unsigned)(row & 7)) << 4);
      int col = wc * 32 + m * 16 + l15;
      boff[m][kk] = (unsigned int)col * 128 + ((((unsigned)(kk * 4 + l4)) ^ (unsigned)(col & 7)) << 4);
    }

  float a8[2][8], inv2[2];
  auto loadA = [&](int h) {
    size_t hoff = (size_t)h * 32 * 4096;
    size_t hlo  = (size_t)h * 32 * 64;
#pragma unroll
    for (int i = 0; i < 2; i++) {
      float s8[8] = {0.f, 0.f, 0.f, 0.f, 0.f, 0.f, 0.f, 0.f};
      float lsum = 0.f;
#pragma unroll
      for (int c = 0; c < C; c++) {
        u16x8_t a = *(const u16x8_t*)(obuf + obase[i][c] + hoff);
        lsum += lptr[i][c][hlo];
#pragma unroll
        for (int k = 0; k < 8; k++) s8[k] += bf2f(a[k]);
      }
      inv2[i] = 1.f / lsum;
#pragma unroll
      for (int k = 0; k < 8; k++) a8[i][k] = s8[k];
    }
  };
  auto writeA = [&](char* dst) {
#pragma unroll
    for (int i = 0; i < 2; i++) {
      u32x4_t w;
      w[0] = cvtpk(a8[i][0] * inv2[i], a8[i][1] * inv2[i]);
      w[1] = cvtpk(a8[i][2] * inv2[i], a8[i][3] * inv2[i]);
      w[2] = cvtpk(a8[i][4] * inv2[i], a8[i][5] * inv2[i]);
      w[3] = cvtpk(a8[i][6] * inv2[i], a8[i][7] * inv2[i]);
      *(u32x4_t*)(dst + awr[i]) = w;
    }
  };

  f32x4_t acc[2][2] = {};

  loadA(0);
#pragma unroll
  for (int i = 0; i < 2; i++) { gload16(bg[i], ldsB + bl[i]); bg[i] += 64; }
  writeA(ldsA);
  __syncthreads();

  int cur = 0;
  for (int t = 0; t < 8; ++t) {
    if (t + 1 < 8) {
      loadA(t + 1);                               // issue combine loads early
      unsigned int db = (cur ^ 1) * BBY;
#pragma unroll
      for (int i = 0; i < 2; i++) { gload16(bg[i], ldsB + db + bl[i]); bg[i] += 64; }
    }
    const char* pa = ldsA + cur * ABY;
    const char* pb = ldsB + cur * BBY;
#pragma unroll
    for (int kk = 0; kk < 2; kk++) {
      bf16x8_t af[2], bfr[2];
#pragma unroll
      for (int m = 0; m < 2; m++) af[m] = *(const bf16x8_t*)(pa + aoff[m][kk]);
#pragma unroll
      for (int n = 0; n < 2; n++) bfr[n] = *(const bf16x8_t*)(pb + boff[n][kk]);
#pragma unroll
      for (int m = 0; m < 2; m++)
#pragma unroll
        for (int n = 0; n < 2; n++)
          acc[m][n] = MFMA16(af[m], bfr[n], acc[m][n]);
    }
    if (t + 1 < 8) writeA(ldsA + (cur ^ 1) * ABY);  // loads landed under MFMA phase
    __syncthreads();
    cur ^= 1;
  }

#pragma unroll
  for (int m = 0; m < 2; m++)
#pragma unroll
    for (int n = 0; n < 2; n++) {
      long col = bcol + wc * 32 + n * 16 + l15;
      float bv = bias[col];
#pragma unroll
      for (int j = 0; j < 4; j++) {
        long row = brow + wr * 32 + m * 16 + l4 * 4 + j;
        Cv[row * DM + col] = f2bf(acc[m][n][j] + bv);
      }
    }
}

// ---------------- flash attention: 8-wave block (128 q-rows), split-KV, no-max, P-in-regs ----------------
// (512,6): 3 blocks/CU is this kernel's verified optimum; (512,8) spills (r14 regression).
template <bool CAUSAL, int C>
__global__ void __launch_bounds__(512, 6) attn_part(const unsigned short* __restrict__ Q, int ldq, int qc0,
                                                    const unsigned short* __restrict__ Kb, int ldk, int kc0,
                                                    const unsigned short* __restrict__ Vt,
                                                    unsigned short* __restrict__ obuf,
                                                    float* __restrict__ lbuf, int Skv) {
  __shared__ __align__(16) unsigned short kt[2][4096];
  __shared__ __align__(16) unsigned short vt[2][4096];
  const int qt = blockIdx.x, bh = blockIdx.y, cch = blockIdx.z;
  const int b = bh >> 3, h = bh & 7;
  const int tid = threadIdx.x, wave = tid >> 6, lane = tid & 63;
  const int sub = wave >> 2, wrow = wave & 3;
  const int l15 = lane & 15, l4 = lane >> 4, q7 = l15 & 7;
  const long qrow0 = (long)b * SQ + qt * 128 + sub * 64;
  const long krow0 = (long)b * Skv;
  const unsigned short* vtb = Vt + (size_t)bh * 64 * Skv;
  const int qoff = qc0 + h * 64, koff = kc0 + h * 64;

  const int ntt = CAUSAL ? (2 * qt + 2) : (Skv >> 6);
  const int t0 = (ntt * cch) / C, t1 = (ntt * (cch + 1)) / C;

  bf16x8_t qf[2];
  {
    long qr = qrow0 + wrow * 16 + l15;
    const unsigned short* qp = Q + qr * (long)ldq + qoff + l4 * 8;
    qf[0] = *(const bf16x8_t*)(qp);
    qf[1] = *(const bf16x8_t*)(qp + 32);
  }

  const unsigned short* kg; const unsigned short* vg;
  {
    int sr = tid >> 3, scc = tid & 7;
    int ssc = scc ^ (sr & 7);
    int rk = (sr & 0x23) | ((sr & 0x0C) << 1) | ((sr & 0x10) >> 2);  // tau(sr)
    kg = Kb + (krow0 + t0 * 64 + rk) * (long)ldk + koff + ssc * 8;
    vg = vtb + (size_t)sr * Skv + t0 * 64 + ssc * 8;
  }
  const unsigned int sld = (unsigned int)tid * 16;
  const long kstep = 64 * (long)ldk;

  const unsigned int pbase = (unsigned int)l15 * 128;
  unsigned int xo[2];
  xo[0] = ((unsigned)(l4 ^ q7)) << 4;
  xo[1] = ((unsigned)((4 + l4) ^ q7)) << 4;

  const int qa = qt * 128 + sub * 64 + wrow * 16 + l15;  // global q row
  const int tdiag = qt * 2 + sub;

  f32x4_t of[4] = {};
  float lrow = 0.f;

  if (t0 < t1) {
    gload16(kg, (char*)kt + sld);
    gload16(vg, (char*)vt + sld);
    kg += kstep; vg += 64;
  }

  int cur = 0;
  for (int t = t0; t < t1; ++t) {
    asm volatile("s_waitcnt vmcnt(0)" ::: "memory");   // this wave's stage loads landed
    __builtin_amdgcn_s_barrier();
    if (t + 1 < t1) {
      unsigned int d = (cur ^ 1) * 8192;
      gload16(kg, (char*)kt + d + sld);
      gload16(vg, (char*)vt + d + sld);
      kg += kstep; vg += 64;
    }
    const char* kbp = (const char*)kt + cur * 8192 + pbase;
    const char* vbp = (const char*)vt + cur * 8192 + pbase;

    f32x4_t sf[4] = {};
    __builtin_amdgcn_s_setprio(1);
#pragma unroll
    for (int n = 0; n < 4; n++) {
      bf16x8_t kf0 = *(const bf16x8_t*)(kbp + xo[0] + n * 2048);
      bf16x8_t kf1 = *(const bf16x8_t*)(kbp + xo[1] + n * 2048);
      sf[n] = MFMA16(kf0, qf[0], sf[n]);
      sf[n] = MFMA16(kf1, qf[1], sf[n]);
    }
    __builtin_amdgcn_s_setprio(0);
    if (CAUSAL && t >= tdiag) {
      int base = (t << 6) + 8 * l4 - qa;   // mask if base + kbn + j > 0
#pragma unroll
      for (int n = 0; n < 4; n++) {
        int kbn = 32 * (n >> 1) + 4 * (n & 1);
#pragma unroll
        for (int j = 0; j < 4; j++)
          if (base + kbn + j > 0) sf[n][j] = -1e30f;
      }
    }
#pragma unroll
    for (int n = 0; n < 4; n++)
#pragma unroll
      for (int j = 0; j < 4; j++) sf[n][j] = exp2fast(sf[n][j]);
    f32x4_t rv = (sf[0] + sf[1]) + (sf[2] + sf[3]);
    lrow += (rv[0] + rv[1]) + (rv[2] + rv[3]);

    union { unsigned int u[4]; bf16x8_t v; } pa0, pa1;
    pa0.u[0] = cvtpk(sf[0][0], sf[0][1]); pa0.u[1] = cvtpk(sf[0][2], sf[0][3]);
    pa0.u[2] = cvtpk(sf[1][0], sf[1][1]); pa0.u[3] = cvtpk(sf[1][2], sf[1][3]);
    pa1.u[0] = cvtpk(sf[2][0], sf[2][1]); pa1.u[1] = cvtpk(sf[2][2], sf[2][3]);
    pa1.u[2] = cvtpk(sf[3][0], sf[3][1]); pa1.u[3] = cvtpk(sf[3][2], sf[3][3]);

    __builtin_amdgcn_s_setprio(1);
#pragma unroll
    for (int n2 = 0; n2 < 4; n2++) {
      bf16x8_t vf0 = *(const bf16x8_t*)(vbp + xo[0] + n2 * 2048);
      bf16x8_t vf1 = *(const bf16x8_t*)(vbp + xo[1] + n2 * 2048);
      of[n2] = MFMA16(pa0.v, vf0, of[n2]);
      of[n2] = MFMA16(pa1.v, vf1, of[n2]);
    }
    __builtin_amdgcn_s_setprio(0);
    cur ^= 1;
  }
  const int blk = (cch * 16 + bh) * 32 + qt * 2 + sub;
  unsigned short* ob = obuf + (size_t)blk * 4096;
#pragma unroll
  for (int j = 0; j < 4; j++) {
    int row = wrow * 16 + l4 * 4 + j;
#pragma unroll
    for (int n2 = 0; n2 < 4; n2++)
      ob[row * 64 + n2 * 16 + l15] = f2bf(of[n2][j]);
  }
  lrow += __shfl_xor(lrow, 16);
  lrow += __shfl_xor(lrow, 32);
  if (l4 == 0) lbuf[(size_t)blk * 64 + wrow * 16 + l15] = lrow;
}

// ---------------- residual + LayerNorm: a (bf16) + residual (fp32 or bf16), bf16 out ----------------
template <bool RF32>
__global__ void __launch_bounds__(256) ln_kernel(const unsigned short* __restrict__ a, const void* __restrict__ rv,
                                                 const float* __restrict__ g, const float* __restrict__ be,
                                                 unsigned short* __restrict__ outb) {
  const int wave = threadIdx.x >> 6, lane = threadIdx.x & 63;
  const long row = (long)blockIdx.x * 4 + wave;
  const int off = lane * 8;
  u16x8_t av = *(const u16x8_t*)(a + row * DM + off);
  float rr[8];
  if (RF32) {
    const float* r = (const float*)rv;
    f32x4_t r0 = *(const f32x4_t*)(r + row * DM + off);
    f32x4_t r1 = *(const f32x4_t*)(r + row * DM + off + 4);
#pragma unroll
    for (int k = 0; k < 4; k++) { rr[k] = r0[k]; rr[k + 4] = r1[k]; }
  } else {
    u16x8_t r8 = *(const u16x8_t*)((const unsigned short*)rv + row * DM + off);
#pragma unroll
    for (int k = 0; k < 8; k++) rr[k] = bf2f(r8[k]);
  }
  float v[8];
  float s = 0.f, ss = 0.f;
#pragma unroll
  for (int k = 0; k < 8; k++) {
    v[k] = bf2f(av[k]) + rr[k];
    s += v[k]; ss += v[k] * v[k];
  }
#pragma unroll
  for (int d = 1; d < 64; d <<= 1) { s += __shfl_xor(s, d); ss += __shfl_xor(ss, d); }
  float mean = s * (1.f / 512.f);
  float var = ss * (1.f / 512.f) - mean * mean;
  float rstd = rsqrtf(var + 1e-6f);
  f32x4_t g0 = *(const f32x4_t*)(g + off), g1 = *(const f32x4_t*)(g + off + 4);
  f32x4_t b0 = *(const f32x4_t*)(be + off), b1 = *(const f32x4_t*)(be + off + 4);
  u16x8_t ob;
#pragma unroll
  for (int k = 0; k < 4; k++) {
    ob[k]     = f2bf((v[k] - mean) * rstd * g0[k] + b0[k]);
    ob[k + 4] = f2bf((v[k + 4] - mean) * rstd * g1[k] + b1[k]);
  }
  *(u16x8_t*)(outb + row * DM + off) = ob;
}

// ---------------- fused: sum 2 bf16 split-K partials + bias + bf16 residual + LayerNorm -> fp32 ----------------
__global__ void __launch_bounds__(256) ln_ffn2(const unsigned short* __restrict__ pbase,
                                               const float* __restrict__ bias,
                                               const unsigned short* __restrict__ resid,
                                               const float* __restrict__ g, const float* __restrict__ be,
                                               float* __restrict__ outf) {
  const int wave = threadIdx.x >> 6, lane = threadIdx.x & 63;
  const long row = (long)blockIdx.x * 4 + wave;
  const size_t stride = (size_t)NT * DM;
  const int off = lane * 8;
  u16x8_t p0 = *(const u16x8_t*)(pbase + row * DM + off);
  u16x8_t p1 = *(const u16x8_t*)(pbase + stride + row * DM + off);
  u16x8_t r8 = *(const u16x8_t*)(resid + row * DM + off);
  f32x4_t b0 = *(const f32x4_t*)(bias + off), b1 = *(const f32x4_t*)(bias + off + 4);
  float v[8];
  float s = 0.f, ss = 0.f;
#pragma unroll
  for (int k = 0; k < 8; k++) {
    v[k] = bf2f(p0[k]) + bf2f(p1[k]) + bf2f(r8[k]) + (k < 4 ? b0[k] : b1[k - 4]);
    s += v[k]; ss += v[k] * v[k];
  }
#pragma unroll
  for (int d = 1; d < 64; d <<= 1) { s += __shfl_xor(s, d); ss += __shfl_xor(ss, d); }
  float mean = s * (1.f / 512.f);
  float var = ss * (1.f / 512.f) - mean * mean;
  float rstd = rsqrtf(var + 1e-6f);
  f32x4_t g0 = *(const f32x4_t*)(g + off), g1 = *(const f32x4_t*)(g + off + 4);
  f32x4_t be0 = *(const f32x4_t*)(be + off), be1 = *(const f32x4_t*)(be + off + 4);
  f32x4_t o0, o1;
#pragma unroll
  for (int k = 0; k < 4; k++) {
    o0[k] = (v[k] - mean) * rstd * g0[k] + be0[k];
    o1[k] = (v[k + 4] - mean) * rstd * g1[k] + be1[k];
  }
  *(f32x4_t*)(outf + row * DM + off) = o0;
  *(f32x4_t*)(outf + row * DM + off + 4) = o1;
}

extern "C" void kernel_launch(void* const* d_in, const int* in_sizes, int n_in,
                              void* d_out, int out_size, void* d_ws, size_t ws_size,
                              hipStream_t stream) {
  (void)in_sizes; (void)n_in; (void)out_size;
  const float* x   = (const float*)d_in[0];
  const float* enc = (const float*)d_in[1];
  const float* w1q = (const float*)d_in[4];  const float* b1q = (const float*)d_in[5];
  const float* w1k = (const float*)d_in[6];  const float* b1k = (const float*)d_in[7];
  const float* w1v = (const float*)d_in[8];  const float* b1v = (const float*)d_in[9];
  const float* w1o = (const float*)d_in[10]; const float* b1o = (const float*)d_in[11];
  const float* w2q = (const float*)d_in[12]; const float* b2q = (const float*)d_in[13];
  const float* w2k = (const float*)d_in[14]; const float* b2k = (const float*)d_in[15];
  const float* w2v = (const float*)d_in[16]; const float* b2v = (const float*)d_in[17];
  const float* w2o = (const float*)d_in[18]; const float* b2o = (const float*)d_in[19];
  const float* fw1 = (const float*)d_in[20]; const float* fb1 = (const float*)d_in[21];
  const float* fw2 = (const float*)d_in[22]; const float* fb2 = (const float*)d_in[23];
  const float* g1  = (const float*)d_in[24]; const float* be1 = (const float*)d_in[25];
  const float* g2  = (const float*)d_in[26]; const float* be2 = (const float*)d_in[27];
  const float* g3  = (const float*)d_in[28]; const float* be3 = (const float*)d_in[29];

  char* ws = (char*)d_ws;
  size_t off = 0;
  auto alloc = [&](size_t bytes) -> void* {
    void* p = ws + off;
    off = (off + bytes + 255) & ~(size_t)255;
    return p;
  };
  unsigned short* xb     = (unsigned short*)alloc((size_t)NT * DM * 2);
  unsigned short* eb     = (unsigned short*)alloc((size_t)NT * DM * 2);
  unsigned short* wqkv1t = (unsigned short*)alloc((size_t)1536 * 512 * 2);
  unsigned short* wo1t   = (unsigned short*)alloc((size_t)512 * 512 * 2);
  unsigned short* wq2t   = (unsigned short*)alloc((size_t)512 * 512 * 2);
  unsigned short* wkv2t  = (unsigned short*)alloc((size_t)1024 * 512 * 2);
  unsigned short* wo2t   = (unsigned short*)alloc((size_t)512 * 512 * 2);
  unsigned short* w1t    = (unsigned short*)alloc((size_t)2048 * 512 * 2);
  unsigned short* w2t    = (unsigned short*)alloc((size_t)512 * 2048 * 2);
  float* bqkv1 = (float*)alloc(1536 * 4);
  float* bq2s  = (float*)alloc(512 * 4);
  float* bkv2  = (float*)alloc(1024 * 4);
  unsigned short* qkv1  = (unsigned short*)alloc((size_t)NT * 1536 * 2);
  unsigned short* vt1   = (unsigned short*)alloc((size_t)16 * 64 * SQ * 2);
  unsigned short* vt2   = (unsigned short*)alloc((size_t)16 * 64 * SQ * 2);
  unsigned short* tmpb  = (unsigned short*)alloc((size_t)NT * DM * 2);
  unsigned short* out1b = (unsigned short*)alloc((size_t)NT * DM * 2);
  unsigned short* kv2   = (unsigned short*)alloc((size_t)NT * 1024 * 2);
  unsigned short* out2b = (unsigned short*)alloc((size_t)NT * DM * 2);
  unsigned short* hbuf  = (unsigned short*)alloc((size_t)NT * 2048 * 2);
  // dedicated scratch
  unsigned short* obuf = (unsigned short*)alloc((size_t)1536 * 4096 * 2);  // 12MB (C<=3)
  float*          lbuf = (float*)alloc((size_t)1536 * 64 * 4);             // 384KB
  unsigned short* pbuf = (unsigned short*)alloc((size_t)2 * NT * DM * 2);  // 8MB bf16 partials
  // reuse dead buffers
  unsigned short* q2 = xb;     // xb dead after merged QKV GEMM
  if (off > ws_size) return;  // workspace too small -> loud validation failure

  // ---- fused preprocessing (1 launch) ----
  prep_all<<<6156, 256, 0, stream>>>(
      x, xb, enc, eb,
      w1q, w1k, w1v, w1o, w2q, w2k, w2v, w2o,
      wqkv1t, wqkv1t + 512 * 512, wqkv1t + 1024 * 512, wo1t,
      wq2t, wkv2t, wkv2t + 512 * 512, wo2t,
      fw1, w1t, fw2, w2t,
      b1q, b1k, b1v, b2q, b2k, b2v, bqkv1, bq2s, bkv2);

  // ---- merged qkv1 + kv2 GEMM with fused V transpose ----
  gemm_qkvkv<<<dim3(64, 20), 256, 0, stream>>>(xb, eb, wqkv1t, wkv2t, bqkv1, bkv2,
                                               qkv1, kv2, vt1, vt2);

  // ---- self-attention block ----
  attn_part<true, 3><<<dim3(16, 16, 3), 512, 0, stream>>>(qkv1, 1536, 0, qkv1, 1536, 512, vt1, obuf, lbuf, SQ);
  gemm_att_o<3><<<dim3(64, 8), 256, 0, stream>>>(obuf, lbuf, wo1t, b1o, tmpb);
  ln_kernel<true><<<1024, 256, 0, stream>>>(tmpb, x, g1, be1, out1b);

  // ---- cross-attention block ----
  gemm_bt<64, 64, 0><<<dim3(64, 8), 256, 0, stream>>>(out1b, DM, wq2t, 512, bq2s, q2, DM, 512);
  attn_part<false, 2><<<dim3(16, 16, 2), 512, 0, stream>>>(q2, DM, 0, kv2, 1024, 0, vt2, obuf, lbuf, SQ);
  gemm_att_o<2><<<dim3(64, 8), 256, 0, stream>>>(obuf, lbuf, wo2t, b2o, tmpb);
  ln_kernel<false><<<1024, 256, 0, stream>>>(tmpb, out1b, g2, be2, out2b);

  // ---- FFN block ----
  gemm_bt<128, 128, 1><<<dim3(32, 16), 256, 0, stream>>>(out2b, DM, w1t, 512, fb1, hbuf, 2048, 512);
  gemm_btk<64, 128><<<dim3(64, 4, 2), 256, 0, stream>>>(hbuf, 2048, w2t, 2048, pbuf, DM, 1024);
  ln_ffn2<<<1024, 256, 0, stream>>>(pbuf, fb2, out2b, g3, be3, (float*)d_out);
}